// Round 11
// baseline (1197.983 us; speedup 1.0000x reference)
//
#include <hip/hip_runtime.h>
#include <hip/hip_bf16.h>
#include <math.h>

#define NN_ 2048

typedef short v8s __attribute__((ext_vector_type(8)));
typedef float v4f __attribute__((ext_vector_type(4)));

__device__ __forceinline__ float geluf(float x){ return 0.5f*x*(1.0f+erff(x*0.70710678118654752440f)); }
__device__ __forceinline__ float gelupf(float x){
  float cdf = 0.5f*(1.0f+erff(x*0.70710678118654752440f));
  float pdf = 0.39894228040143267794f*expf(-0.5f*x*x);
  return cdf + x*pdf;
}
__device__ __forceinline__ float sigm(float x){ return 1.0f/(1.0f+expf(-x)); }

__device__ __forceinline__ unsigned short f2bs(float f){
  __hip_bfloat16 h = __float2bfloat16(f);
  return __builtin_bit_cast(unsigned short, h);
}
__device__ __forceinline__ float bs2f(unsigned short u){
  unsigned v = ((unsigned)u)<<16;
  return __builtin_bit_cast(float, v);
}
__device__ __forceinline__ void hilo(float v, unsigned short &h, unsigned short &l){
  h = f2bs(v); l = f2bs(v - bs2f(h));
}
// XOR swizzle folding (r>>2): transpose-staging writes spread across bank groups
__device__ __forceinline__ int swz(int r, int k){
  return r*128 + ((((k>>3) ^ (r&15) ^ ((r>>2)&15)) & 15)<<3) + (k&7);
}
__device__ __forceinline__ int swz64(int r, int k){
  return r*64 + ((((k>>3) ^ (r&7) ^ ((r>>2)&7)) & 7)<<3) + (k&7);
}
__device__ __forceinline__ int swz32(int r, int k){
  return r*32 + ((((k>>3) ^ (r&3) ^ ((r>>2)&3)) & 3)<<3) + (k&7);
}

// ---------------- rmsnorm of seq with store/retrieve gains ----------------
__global__ __launch_bounds__(256) void k_rmsnorm(const float* __restrict__ seq, const float* __restrict__ gs,
                          const float* __restrict__ gr, float* __restrict__ S, float* __restrict__ SR){
  int tok = blockIdx.x;
  const float* row = seq + (size_t)tok*512;
  int tid = threadIdx.x;
  float x0 = row[tid];
  float x1 = row[tid+256];
  float ss = x0*x0 + x1*x1;
  #pragma unroll
  for (int o=32;o>0;o>>=1) ss += __shfl_down(ss, o, 64);
  __shared__ float wsum[4];
  int wid = tid>>6, lid = tid&63;
  if (lid==0) wsum[wid]=ss;
  __syncthreads();
  float tot = wsum[0]+wsum[1]+wsum[2]+wsum[3];
  float r = rsqrtf(tot*(1.0f/512.0f) + 1e-6f);
  size_t o0 = (size_t)tok*512 + tid;
  S[o0]      = x0*r*gs[tid];
  S[o0+256]  = x1*r*gs[tid+256];
  SR[o0]     = x0*r*gr[tid];
  SR[o0+256] = x1*r*gr[tid+256];
}

// ---------------- MFMA GEMM: O[4096x512] = X @ Wt, hi/lo, 64x128 tiles ----------------
__global__ __launch_bounds__(256) void k_gemm_mfma(const float* __restrict__ X, const float* __restrict__ Wt,
                                                   float* __restrict__ O){
  int m0 = blockIdx.x*64, n0 = blockIdx.y*128;
  __shared__ unsigned short Xh[4096], Xl[4096], Wh[8192], Wl[8192];
  int tid = threadIdx.x, w = tid>>6, lane = tid&63, n_l = lane&15, quad = lane>>4;
  v4f acc[8];
  #pragma unroll
  for (int j=0;j<8;j++){ v4f z={0.f,0.f,0.f,0.f}; acc[j]=z; }
  for (int kc=0; kc<8; kc++){
    int k0 = kc*64;
    __syncthreads();
    for (int it=0; it<4; it++){
      int idx = it*1024 + tid*4;
      int r = idx>>6, k = idx&63;
      float4 v = *(const float4*)(X + (size_t)(m0+r)*512 + k0 + k);
      union { unsigned long long q; unsigned short s[4]; } uh, ul;
      hilo(v.x,uh.s[0],ul.s[0]); hilo(v.y,uh.s[1],ul.s[1]);
      hilo(v.z,uh.s[2],ul.s[2]); hilo(v.w,uh.s[3],ul.s[3]);
      int p = swz64(r,k);
      *(unsigned long long*)&Xh[p] = uh.q;
      *(unsigned long long*)&Xl[p] = ul.q;
    }
    for (int it=0; it<8; it++){
      int idx = it*1024 + tid*4;
      int k = idx>>7, n = idx&127;
      float4 v = *(const float4*)(Wt + (size_t)(k0+k)*512 + n0 + n);
      unsigned short hh,ll;
      hilo(v.x,hh,ll); Wh[swz64(n+0,k)]=hh; Wl[swz64(n+0,k)]=ll;
      hilo(v.y,hh,ll); Wh[swz64(n+1,k)]=hh; Wl[swz64(n+1,k)]=ll;
      hilo(v.z,hh,ll); Wh[swz64(n+2,k)]=hh; Wl[swz64(n+2,k)]=ll;
      hilo(v.w,hh,ll); Wh[swz64(n+3,k)]=hh; Wl[swz64(n+3,k)]=ll;
    }
    __syncthreads();
    #pragma unroll
    for (int ks=0; ks<2; ks++){
      int kf = ks*32 + quad*8;
      v8s ah = *(const v8s*)&Xh[swz64(16*w + n_l, kf)];
      v8s al = *(const v8s*)&Xl[swz64(16*w + n_l, kf)];
      #pragma unroll
      for (int nt=0; nt<8; nt++){
        v8s bh = *(const v8s*)&Wh[swz64(nt*16+n_l, kf)];
        v8s bl = *(const v8s*)&Wl[swz64(nt*16+n_l, kf)];
        acc[nt] = __builtin_amdgcn_mfma_f32_16x16x32_bf16(ah, bh, acc[nt], 0,0,0);
        acc[nt] = __builtin_amdgcn_mfma_f32_16x16x32_bf16(ah, bl, acc[nt], 0,0,0);
        acc[nt] = __builtin_amdgcn_mfma_f32_16x16x32_bf16(al, bh, acc[nt], 0,0,0);
      }
    }
  }
  #pragma unroll
  for (int nt=0; nt<8; nt++)
    #pragma unroll
    for (int r=0;r<4;r++)
      O[(size_t)(m0 + 16*w + quad*4 + r)*512 + n0 + nt*16 + n_l] = acc[nt][r];
}

// ---------------- lr/gate per token, pooled->mom/dec per chunk ----------------
__global__ __launch_bounds__(256) void k_small(const float* __restrict__ S, const float* __restrict__ SR,
    const float* __restrict__ Wlr, const float* __restrict__ blr, const float* __restrict__ Wm,
    const float* __restrict__ bm, const float* __restrict__ Wd, const float* __restrict__ bd,
    const float* __restrict__ Wgate,
    float* __restrict__ LRb, float* __restrict__ GATEb, float* __restrict__ MOMb, float* __restrict__ DECb){
  int bc = blockIdx.x;            // b*32 + ci
  int b = bc>>5, ci = bc&31;
  int tid = threadIdx.x;
  int t = tid>>2, h = tid&3;
  size_t tokbase = (size_t)b*NN_ + (size_t)ci*64;
  __shared__ float pool[512];
  for (int c=tid; c<512; c+=256){
    float s=0;
    for (int t2=0;t2<64;t2++) s += S[(tokbase+t2)*512 + c];
    pool[c] = s*(1.0f/64.0f);
  }
  size_t tok = tokbase + t;
  const float* srow = S + tok*512;
  const float* srrow = SR + tok*512;
  float accl=0, accg=0;
  for (int d=0; d<512; d++){
    accl += srow[d]*Wlr[d*4+h];
    accg += srrow[d]*Wgate[d*4+h];
  }
  accl += blr[h];
  LRb[tok*4+h] = sigm(accl);
  GATEb[tok*4+h] = sigm(accg);
  __syncthreads();
  if (tid<8){
    int hh = tid&3, which = tid>>2;
    float a=0;
    const float* Wx = which? Wd : Wm;
    for (int d=0; d<512; d++) a += pool[d]*Wx[d*4+hh];
    a += which? bd[hh] : bm[hh];
    float v = sigm(a);
    size_t o = ((size_t)b*4+hh)*32 + ci;
    if (which) DECb[o]=v; else MOMb[o]=v;
  }
}

// ---------------- fused memory-MLP forward + rmsnorm backward (MFMA, 512 thr, 4x2 wave grid) ----------------
__global__ __launch_bounds__(512) void k_fwd(const float* __restrict__ Kb, const float* __restrict__ Vb,
    const float* __restrict__ LRb, const float* __restrict__ mw1, const float* __restrict__ mw2,
    const float* __restrict__ mgamma, float* __restrict__ H1T, float* __restrict__ DH2,
    float* __restrict__ GG){
  int inst = blockIdx.x;
  int ci = inst & 31, h = (inst>>5)&3, b = inst>>7;
  size_t tok0 = (size_t)b*NN_ + (size_t)ci*64;
  int tid = threadIdx.x, w = tid>>6, lane = tid&63, n_l = lane&15, quad = lane>>4;
  int wm = w&3, wn = w>>2;          // wm: token-quarter (16 rows), wn: N-half
  __shared__ unsigned short xh[8192];              // [64 t][128 d] swz, hi only
  __shared__ unsigned short wbh[8192], wbl[8192];  // weight tile
  __shared__ unsigned short ash[4096], asl[4096];  // gelu(h1) tile [64 t][64 j] swz64
  const float* w1 = mw1 + (size_t)h*65536;  // [128 d][512 j]
  const float* w2 = mw2 + (size_t)h*65536;  // [512 j][128 d]
  for (int it=0; it<4; it++){
    int idx = it*2048 + tid*4;
    int r = idx>>7, d = idx&127;
    float4 v = *(const float4*)(Kb + (tok0+r)*512 + h*128 + d);
    int p = swz(r,d);
    *(unsigned*)&xh[p]   = (unsigned)f2bs(v.x)|((unsigned)f2bs(v.y)<<16);
    *(unsigned*)&xh[p+2] = (unsigned)f2bs(v.z)|((unsigned)f2bs(v.w)<<16);
  }
  v4f acc2[4];
  #pragma unroll
  for (int j=0;j<4;j++){ v4f z={0.f,0.f,0.f,0.f}; acc2[j]=z; }
  for (int jt=0; jt<8; jt++){
    int j0 = jt*64;
    __syncthreads();
    for (int it=0; it<4; it++){
      int idx = it*2048 + tid*4;
      int d = idx>>6, jj = idx&63;
      float4 v = *(const float4*)(w1 + (size_t)d*512 + j0 + jj);
      unsigned short hh,ll;
      hilo(v.x,hh,ll); wbh[swz(jj+0,d)]=hh; wbl[swz(jj+0,d)]=ll;
      hilo(v.y,hh,ll); wbh[swz(jj+1,d)]=hh; wbl[swz(jj+1,d)]=ll;
      hilo(v.z,hh,ll); wbh[swz(jj+2,d)]=hh; wbl[swz(jj+2,d)]=ll;
      hilo(v.w,hh,ll); wbh[swz(jj+3,d)]=hh; wbl[swz(jj+3,d)]=ll;
    }
    __syncthreads();
    v4f acc1[2];
    #pragma unroll
    for (int nt=0; nt<2; nt++){ v4f z={0.f,0.f,0.f,0.f}; acc1[nt]=z; }
    #pragma unroll
    for (int ks=0; ks<4; ks++){
      int kf = ks*32 + quad*8;
      v8s av = *(const v8s*)&xh[swz(16*wm + n_l, kf)];
      #pragma unroll
      for (int nt=0; nt<2; nt++){
        int jj = wn*32 + nt*16 + n_l;
        v8s bh = *(const v8s*)&wbh[swz(jj, kf)];
        v8s bl = *(const v8s*)&wbl[swz(jj, kf)];
        acc1[nt] = __builtin_amdgcn_mfma_f32_16x16x32_bf16(av, bh, acc1[nt], 0,0,0);
        acc1[nt] = __builtin_amdgcn_mfma_f32_16x16x32_bf16(av, bl, acc1[nt], 0,0,0);
      }
    }
    #pragma unroll
    for (int nt=0; nt<2; nt++){
      int jj = wn*32 + nt*16 + n_l;
      float4 hv4;
      hv4.x = acc1[nt][0]; hv4.y = acc1[nt][1]; hv4.z = acc1[nt][2]; hv4.w = acc1[nt][3];
      *(float4*)(H1T + (size_t)inst*32768 + (size_t)(j0+jj)*64 + 16*wm + quad*4) = hv4;
      #pragma unroll
      for (int r=0;r<4;r++){
        int t = 16*wm + quad*4 + r;
        float g = geluf(acc1[nt][r]);
        unsigned short gh = f2bs(g);
        ash[swz64(t, jj)] = gh;
        asl[swz64(t, jj)] = f2bs(g - bs2f(gh));
      }
    }
    __syncthreads();
    for (int it=0; it<4; it++){
      int idx = it*2048 + tid*4;
      int jj = idx>>7, d = idx&127;
      float4 v = *(const float4*)(w2 + (size_t)(j0+jj)*128 + d);
      unsigned short hh,ll;
      hilo(v.x,hh,ll); wbh[swz64(d+0,jj)]=hh; wbl[swz64(d+0,jj)]=ll;
      hilo(v.y,hh,ll); wbh[swz64(d+1,jj)]=hh; wbl[swz64(d+1,jj)]=ll;
      hilo(v.z,hh,ll); wbh[swz64(d+2,jj)]=hh; wbl[swz64(d+2,jj)]=ll;
      hilo(v.w,hh,ll); wbh[swz64(d+3,jj)]=hh; wbl[swz64(d+3,jj)]=ll;
    }
    __syncthreads();
    #pragma unroll
    for (int ks=0; ks<2; ks++){
      int kf = ks*32 + quad*8;
      v8s ah = *(const v8s*)&ash[swz64(16*wm + n_l, kf)];
      v8s al = *(const v8s*)&asl[swz64(16*wm + n_l, kf)];
      #pragma unroll
      for (int nt=0; nt<4; nt++){
        int dc = wn*64 + nt*16 + n_l;
        v8s bh = *(const v8s*)&wbh[swz64(dc, kf)];
        v8s bl = *(const v8s*)&wbl[swz64(dc, kf)];
        acc2[nt] = __builtin_amdgcn_mfma_f32_16x16x32_bf16(ah, bh, acc2[nt], 0,0,0);
        acc2[nt] = __builtin_amdgcn_mfma_f32_16x16x32_bf16(ah, bl, acc2[nt], 0,0,0);
        acc2[nt] = __builtin_amdgcn_mfma_f32_16x16x32_bf16(al, bh, acc2[nt], 0,0,0);
      }
    }
  }
  // epilogue: rmsnorm backward; rows split over wm, cols split over wn
  float* red = (float*)wbh;   // [0..127] sgg, [128..255] ssh[2][64], [256..383] doth[2][64]
  __syncthreads();
  if (tid<128) red[tid]=0.0f;
  float ss[4] = {0,0,0,0};
  #pragma unroll
  for (int nt=0; nt<4; nt++)
    #pragma unroll
    for (int r=0;r<4;r++) ss[r] += acc2[nt][r]*acc2[nt][r];
  #pragma unroll
  for (int m=1;m<16;m<<=1)
    #pragma unroll
    for (int r=0;r<4;r++) ss[r] += __shfl_xor(ss[r], m, 64);
  if (n_l==0){
    #pragma unroll
    for (int r=0;r<4;r++) red[128 + wn*64 + 16*wm + quad*4 + r] = ss[r];
  }
  __syncthreads();
  float rr[4];
  #pragma unroll
  for (int r=0;r<4;r++){
    int row = 16*wm + quad*4 + r;
    float tot = red[128 + row] + red[128 + 64 + row];
    rr[r] = rsqrtf(tot*(1.0f/128.0f) + 1e-6f);
  }
  float gv[4];
  #pragma unroll
  for (int nt=0; nt<4; nt++) gv[nt] = mgamma[h*128 + wn*64 + nt*16 + n_l];
  float lrv[4];
  #pragma unroll
  for (int r=0;r<4;r++) lrv[r] = LRb[(tok0 + 16*wm + quad*4 + r)*4 + h]*(2.0f/128.0f);
  float dnv[4][4]; float dot[4]={0,0,0,0}; float ggp[4];
  #pragma unroll
  for (int nt=0; nt<4; nt++) ggp[nt]=0.0f;
  #pragma unroll
  for (int nt=0; nt<4; nt++)
    #pragma unroll
    for (int r=0;r<4;r++){
      int t = 16*wm + quad*4 + r;
      int d = wn*64 + nt*16 + n_l;
      float xv = Kb[(tok0+t)*512 + h*128 + d];
      float vv = Vb[(tok0+t)*512 + h*128 + d];
      float nval = acc2[nt][r]*rr[r];
      float pred = nval*gv[nt] + xv;
      float dp = lrv[r]*(pred - vv);
      ggp[nt] += dp*nval;
      float dn = dp*gv[nt];
      dnv[nt][r] = dn;
      dot[r] += dn*acc2[nt][r];
    }
  #pragma unroll
  for (int nt=0; nt<4; nt++) atomicAdd(&red[wn*64 + nt*16 + n_l], ggp[nt]);
  #pragma unroll
  for (int m=1;m<16;m<<=1)
    #pragma unroll
    for (int r=0;r<4;r++) dot[r] += __shfl_xor(dot[r], m, 64);
  if (n_l==0){
    #pragma unroll
    for (int r=0;r<4;r++) red[256 + wn*64 + 16*wm + quad*4 + r] = dot[r];
  }
  __syncthreads();
  #pragma unroll
  for (int r=0;r<4;r++){
    int row = 16*wm + quad*4 + r;
    float dtot = red[256 + row] + red[256 + 64 + row];
    float dt = dtot*rr[r]*rr[r]*rr[r]*(1.0f/128.0f);
    #pragma unroll
    for (int nt=0; nt<4; nt++){
      int d = wn*64 + nt*16 + n_l;
      DH2[(size_t)inst*8192 + (size_t)row*128 + d] = rr[r]*dnv[nt][r] - dt*acc2[nt][r];
    }
  }
  __syncthreads();
  if (tid<128) GG[(size_t)inst*128+tid] = -red[tid];
}

// ---------------- dw2 (MFMA, 512 thr): G2T[d][j] = -sum_t dh2[t,d]*gelu(h1[t,j]); norm2[256+inst] ----------------
__global__ __launch_bounds__(512) void k_dw2(const float* __restrict__ DH2, const float* __restrict__ H1T,
                                             float* __restrict__ G2T, float* __restrict__ norm2){
  int inst = blockIdx.x;
  int tid = threadIdx.x, w = tid>>6, lane = tid&63, n_l = lane&15, quad = lane>>4;
  __shared__ unsigned short d2h[8192], d2l[8192];  // dh2^T [128 d][64 t] swz64 hi/lo
  __shared__ unsigned short ath[8192], atl[8192];  // gelu(h1)^T tile [128 j][64 t] swz64 hi/lo
  float nrm = 0.0f;
  for (int it=0; it<4; it++){
    int idx = it*2048 + tid*4;
    int t = idx>>7, d = idx&127;
    float4 v = *(const float4*)(DH2 + (size_t)inst*8192 + idx);
    unsigned short hh,ll;
    hilo(v.x,hh,ll); d2h[swz64(d+0,t)]=hh; d2l[swz64(d+0,t)]=ll;
    hilo(v.y,hh,ll); d2h[swz64(d+1,t)]=hh; d2l[swz64(d+1,t)]=ll;
    hilo(v.z,hh,ll); d2h[swz64(d+2,t)]=hh; d2l[swz64(d+2,t)]=ll;
    hilo(v.w,hh,ll); d2h[swz64(d+3,t)]=hh; d2l[swz64(d+3,t)]=ll;
  }
  for (int jt=0; jt<4; jt++){
    int j0 = jt*128;
    if (jt) __syncthreads();
    for (int it=0; it<4; it++){
      int idx = it*2048 + tid*4;
      int j = idx>>6, t = idx&63;
      float4 v = *(const float4*)(H1T + (size_t)inst*32768 + (size_t)(j0+j)*64 + t);
      union { unsigned long long q; unsigned short s[4]; } uh, ul;
      float g0=geluf(v.x), g1=geluf(v.y), g2=geluf(v.z), g3=geluf(v.w);
      hilo(g0,uh.s[0],ul.s[0]); hilo(g1,uh.s[1],ul.s[1]);
      hilo(g2,uh.s[2],ul.s[2]); hilo(g3,uh.s[3],ul.s[3]);
      int p = swz64(j,t);
      *(unsigned long long*)&ath[p] = uh.q;
      *(unsigned long long*)&atl[p] = ul.q;
    }
    __syncthreads();
    v4f acc[8];
    #pragma unroll
    for (int j=0;j<8;j++){ v4f z={0.f,0.f,0.f,0.f}; acc[j]=z; }
    #pragma unroll
    for (int ks=0; ks<2; ks++){
      int kf = ks*32 + quad*8;
      v8s ah = *(const v8s*)&d2h[swz64(16*w + n_l, kf)];
      v8s al = *(const v8s*)&d2l[swz64(16*w + n_l, kf)];
      #pragma unroll
      for (int nt=0; nt<8; nt++){
        v8s bh = *(const v8s*)&ath[swz64(nt*16+n_l, kf)];
        v8s bl = *(const v8s*)&atl[swz64(nt*16+n_l, kf)];
        acc[nt] = __builtin_amdgcn_mfma_f32_16x16x32_bf16(ah, bh, acc[nt], 0,0,0);
        acc[nt] = __builtin_amdgcn_mfma_f32_16x16x32_bf16(ah, bl, acc[nt], 0,0,0);
        acc[nt] = __builtin_amdgcn_mfma_f32_16x16x32_bf16(al, bh, acc[nt], 0,0,0);
      }
    }
    #pragma unroll
    for (int nt=0; nt<8; nt++)
      #pragma unroll
      for (int r=0;r<4;r++){
        float gvv = acc[nt][r];
        nrm += gvv*gvv;
        G2T[(size_t)inst*65536 + (size_t)(16*w + quad*4 + r)*512 + j0 + nt*16 + n_l] = -gvv;
      }
  }
  #pragma unroll
  for (int o=32;o>0;o>>=1) nrm += __shfl_down(nrm, o, 64);
  __syncthreads();
  float* red8 = (float*)d2h;
  if (lane==0) red8[w]=nrm;
  __syncthreads();
  if (tid==0){
    float s=0;
    #pragma unroll
    for (int i=0;i<8;i++) s+=red8[i];
    norm2[256+inst] = s;
  }
}

// ---------------- dw1 (MFMA, 512 thr, fused): da^T = w2@dh2^T; dh1 = da*gelu'; G1 = -x^T@dh1 ----------------
__global__ __launch_bounds__(512) void k_dw1(const float* __restrict__ Kb, const float* __restrict__ DH2,
    const float* __restrict__ H1T, const float* __restrict__ mw2, float* __restrict__ G1,
    float* __restrict__ norm2){
  int inst = blockIdx.x;
  int ci = inst&31, h=(inst>>5)&3, b=inst>>7;
  size_t tok0 = (size_t)b*NN_ + (size_t)ci*64;
  int tid = threadIdx.x, w = tid>>6, lane = tid&63, n_l = lane&15, quad = lane>>4;
  int wm = w&3, wn = w>>2;
  __shared__ unsigned short dh2h[8192];   // dh2 [64 t][128 d] swz, hi
  __shared__ unsigned short xth[8192];    // x^T [128 d][64 t] swz64, hi
  __shared__ unsigned short wb[16384];    // w2 tile hi/lo; reused for dh1T hi/lo
  unsigned short* wbl = wb + 8192;
  unsigned short* d1h = wb;
  unsigned short* d1l = wb + 4096;
  const float* w2 = mw2 + (size_t)h*65536;
  float nrm = 0.0f;
  for (int it=0; it<4; it++){
    int idx = it*2048 + tid*4;
    int t = idx>>7, d = idx&127;
    float4 v = *(const float4*)(DH2 + (size_t)inst*8192 + idx);
    union { unsigned long long q; unsigned short s[4]; } uh;
    uh.s[0]=f2bs(v.x); uh.s[1]=f2bs(v.y); uh.s[2]=f2bs(v.z); uh.s[3]=f2bs(v.w);
    *(unsigned long long*)&dh2h[swz(t,d)] = uh.q;
  }
  for (int it=0; it<4; it++){
    int idx = it*2048 + tid*4;
    int t = idx>>7, d = idx&127;
    float4 v = *(const float4*)(Kb + (tok0+t)*512 + h*128 + d);
    xth[swz64(d+0,t)] = f2bs(v.x);
    xth[swz64(d+1,t)] = f2bs(v.y);
    xth[swz64(d+2,t)] = f2bs(v.z);
    xth[swz64(d+3,t)] = f2bs(v.w);
  }
  for (int jt=0; jt<8; jt++){
    int j0 = jt*64;
    __syncthreads();
    for (int it=0; it<4; it++){
      int idx = it*2048 + tid*4;
      int jj = idx>>7, d = idx&127;
      float4 v = *(const float4*)(w2 + (size_t)(j0+jj)*128 + d);
      union { unsigned long long q; unsigned short s[4]; } uh, ul;
      hilo(v.x,uh.s[0],ul.s[0]); hilo(v.y,uh.s[1],ul.s[1]);
      hilo(v.z,uh.s[2],ul.s[2]); hilo(v.w,uh.s[3],ul.s[3]);
      int p = swz(jj,d);
      *(unsigned long long*)&wb[p]  = uh.q;
      *(unsigned long long*)&wbl[p] = ul.q;
    }
    __syncthreads();
    // daT: wave (wm,wn): M j-row 16*wm; N t-tiles wn*32+{0,16}; K=128 d
    v4f da[2];
    #pragma unroll
    for (int nt=0; nt<2; nt++){ v4f z={0.f,0.f,0.f,0.f}; da[nt]=z; }
    #pragma unroll
    for (int ks=0; ks<4; ks++){
      int kf = ks*32 + quad*8;
      v8s a_h = *(const v8s*)&wb[swz(16*wm + n_l, kf)];
      v8s a_l = *(const v8s*)&wbl[swz(16*wm + n_l, kf)];
      #pragma unroll
      for (int nt=0; nt<2; nt++){
        v8s bv = *(const v8s*)&dh2h[swz(wn*32 + nt*16 + n_l, kf)];
        da[nt] = __builtin_amdgcn_mfma_f32_16x16x32_bf16(a_h, bv, da[nt], 0,0,0);
        da[nt] = __builtin_amdgcn_mfma_f32_16x16x32_bf16(a_l, bv, da[nt], 0,0,0);
      }
    }
    __syncthreads();
    // dh1T = daT * gelu'(h1T): wave covers (16 j) x (32 t)
    #pragma unroll
    for (int nt=0; nt<2; nt++)
      #pragma unroll
      for (int r=0;r<4;r++){
        int jl = 16*wm + quad*4 + r;
        int t = wn*32 + nt*16 + n_l;
        float hv = H1T[(size_t)inst*32768 + (size_t)(j0+jl)*64 + t];
        float d1 = da[nt][r]*gelupf(hv);
        unsigned short hs = f2bs(d1);
        d1h[swz64(jl,t)] = hs;
        d1l[swz64(jl,t)] = f2bs(d1 - bs2f(hs));
      }
    __syncthreads();
    // G1 tile: wave w: M d-row 16w; N=64 j (4 nt); K=64 t
    v4f g[4];
    #pragma unroll
    for (int nt=0; nt<4; nt++){ v4f z={0.f,0.f,0.f,0.f}; g[nt]=z; }
    #pragma unroll
    for (int ks=0; ks<2; ks++){
      int kf = ks*32 + quad*8;
      v8s a_ = *(const v8s*)&xth[swz64(16*w + n_l, kf)];
      #pragma unroll
      for (int nt=0; nt<4; nt++){
        v8s bh = *(const v8s*)&d1h[swz64(nt*16+n_l, kf)];
        v8s bl = *(const v8s*)&d1l[swz64(nt*16+n_l, kf)];
        g[nt] = __builtin_amdgcn_mfma_f32_16x16x32_bf16(a_, bh, g[nt], 0,0,0);
        g[nt] = __builtin_amdgcn_mfma_f32_16x16x32_bf16(a_, bl, g[nt], 0,0,0);
      }
    }
    #pragma unroll
    for (int nt=0; nt<4; nt++)
      #pragma unroll
      for (int r=0;r<4;r++){
        float gvv = g[nt][r];
        nrm += gvv*gvv;
        G1[(size_t)inst*65536 + (size_t)(16*w + quad*4 + r)*512 + j0 + nt*16 + n_l] = -gvv;
      }
  }
  #pragma unroll
  for (int o=32;o>0;o>>=1) nrm += __shfl_down(nrm, o, 64);
  __syncthreads();
  float* red8 = (float*)wb;
  if (lane==0) red8[w]=nrm;
  __syncthreads();
  if (tid==0){
    float s=0;
    #pragma unroll
    for (int i=0;i<8;i++) s+=red8[i];
    norm2[inst] = s;
  }
}

// ---------------- NS fused A+B (512 thr): A = t@t^T (regs); acc seeded (CB/CC)A; B = CC*(A@A) ----------------
__global__ __launch_bounds__(512) void k_nsAB(const float* __restrict__ G1, const float* __restrict__ G2T,
                                              const float* __restrict__ norm2,
                                              unsigned short* __restrict__ ABh, unsigned short* __restrict__ ABl,
                                              int first){
  int m = blockIdx.x;
  const float* t = (m<256)? (G1 + (size_t)m*65536) : (G2T + (size_t)(m-256)*65536);
  float scl = first ? 1.0f/fmaxf(sqrtf(norm2[m]), 1e-7f) : 1.0f;
  __shared__ unsigned short th[16384];
  __shared__ unsigned short tl[16384];
  int tid = threadIdx.x;
  int w = tid>>6, lane = tid&63;     // w: 0..7, rows 16w
  int n = lane&15, quad = lane>>4;
  v4f acc[8];
  #pragma unroll
  for (int j=0;j<8;j++){ v4f z = {0.f,0.f,0.f,0.f}; acc[j]=z; }
  for (int c=0;c<4;c++){
    int k0 = c*128;
    for (int it=0; it<8; it++){
      int idx = it*2048 + tid*4;
      int r = idx>>7, k = idx&127;
      float4 v = *(const float4*)(t + (size_t)r*512 + k0 + k);
      v.x*=scl; v.y*=scl; v.z*=scl; v.w*=scl;
      union { unsigned long long q; unsigned short s[4]; } uh, ulw;
      hilo(v.x,uh.s[0],ulw.s[0]); hilo(v.y,uh.s[1],ulw.s[1]);
      hilo(v.z,uh.s[2],ulw.s[2]); hilo(v.w,uh.s[3],ulw.s[3]);
      *(unsigned long long*)&th[swz(r,k)] = uh.q;
      *(unsigned long long*)&tl[swz(r,k)] = ulw.q;
    }
    __syncthreads();
    for (int kk=0; kk<128; kk+=32){
      int kf = kk + quad*8;
      v8s ah = *(const v8s*)&th[swz(16*w + n, kf)];
      v8s al = *(const v8s*)&tl[swz(16*w + n, kf)];
      #pragma unroll
      for (int j=0;j<8;j++){
        v8s bh = *(const v8s*)&th[swz(j*16 + n, kf)];
        v8s bl = *(const v8s*)&tl[swz(j*16 + n, kf)];
        acc[j] = __builtin_amdgcn_mfma_f32_16x16x32_bf16(ah, bh, acc[j], 0,0,0);
        acc[j] = __builtin_amdgcn_mfma_f32_16x16x32_bf16(ah, bl, acc[j], 0,0,0);
        acc[j] = __builtin_amdgcn_mfma_f32_16x16x32_bf16(al, bh, acc[j], 0,0,0);
      }
    }
    __syncthreads();
  }
  const float CB=-4.775f, CC=2.0315f, CBoverCC = CB/CC;
  #pragma unroll
  for (int j=0;j<8;j++)
    #pragma unroll
    for (int r=0;r<4;r++){
      int row = 16*w + quad*4 + r;
      int col = j*16 + n;
      float av = acc[j][r];
      unsigned short hs, ls;
      hilo(av, hs, ls);
      th[swz(row,col)] = hs;
      tl[swz(row,col)] = ls;
      acc[j][r] = CBoverCC*av;
    }
  __syncthreads();
  for (int kk=0; kk<128; kk+=32){
    int kf = kk + quad*8;
    v8s ah = *(const v8s*)&th[swz(16*w + n, kf)];
    v8s al = *(const v8s*)&tl[swz(16*w + n, kf)];
    #pragma unroll
    for (int j=0;j<8;j++){
      v8s bh = *(const v8s*)&th[swz(j*16 + n, kf)];
      v8s bl = *(const v8s*)&tl[swz(j*16 + n, kf)];
      acc[j] = __builtin_amdgcn_mfma_f32_16x16x32_bf16(ah, bh, acc[j], 0,0,0);
      acc[j] = __builtin_amdgcn_mfma_f32_16x16x32_bf16(ah, bl, acc[j], 0,0,0);
      acc[j] = __builtin_amdgcn_mfma_f32_16x16x32_bf16(al, bh, acc[j], 0,0,0);
    }
  }
  __syncthreads();
  #pragma unroll
  for (int j=0;j<8;j++)
    #pragma unroll
    for (int r=0;r<4;r++){
      int row = 16*w + quad*4 + r;
      int col = j*16 + n;
      float v = CC*acc[j][r];
      unsigned short hs, ls;
      hilo(v, hs, ls);
      th[row*128+col] = hs;
      tl[row*128+col] = ls;
    }
  __syncthreads();
  for (int it=0; it<4; it++){
    int idx = it*4096 + tid*8;
    *(v8s*)&ABh[(size_t)m*16384 + idx] = *(const v8s*)&th[idx];
    *(v8s*)&ABl[(size_t)m*16384 + idx] = *(const v8s*)&tl[idx];
  }
}

// ---------------- NS step 2 (512 thr, 32KB staging, coalesced half-Zs epilogue) ----------------
__global__ __launch_bounds__(512) void k_nsZ(float* __restrict__ G1, float* __restrict__ G2T,
                                             const unsigned short* __restrict__ ABh, const unsigned short* __restrict__ ABl,
                                             const float* __restrict__ norm2, int first){
  int blk = blockIdx.x;
  int m = (blk>>5)*8 + (blk&7);
  int s = (blk>>3)&3, c0 = s*128;
  float* t = (m<256)? (G1 + (size_t)m*65536) : (G2T + (size_t)(m-256)*65536);
  float scl = first ? 1.0f/fmaxf(sqrtf(norm2[m]), 1e-7f) : 1.0f;
  __shared__ __align__(16) unsigned char smem[32768];
  unsigned short* Bh = (unsigned short*)smem;   // [128 r][32 k] swz32 hi
  unsigned short* Bl = Bh + 4096;
  unsigned short* uh = Bh + 8192;               // u [128 j][32 k] swz32 hi
  unsigned short* ul = Bh + 12288;
  float* Zs = (float*)smem;                     // epilogue alias [64][128] fp32 (half)
  int tid = threadIdx.x;
  int w = tid>>6, lane = tid&63;      // w: 0..7, rows 16w
  int n = lane&15, quad = lane>>4;
  v4f acc[8];
  #pragma unroll
  for (int j=0;j<8;j++){ v4f z = {0.f,0.f,0.f,0.f}; acc[j]=z; }
  for (int c=0;c<4;c++){
    int k0 = c*32;
    if (c) __syncthreads();
    {
      int idx = tid*8;
      int r = idx>>5, k = idx&31;
      *(v8s*)&Bh[swz32(r,k)] = *(const v8s*)&ABh[(size_t)m*16384 + (size_t)r*128 + k0 + k];
      *(v8s*)&Bl[swz32(r,k)] = *(const v8s*)&ABl[(size_t)m*16384 + (size_t)r*128 + k0 + k];
    }
    for (int it=0; it<2; it++){
      int idx = it*2048 + tid*4;
      int kr = idx>>7, j = idx&127;
      float4 v = *(const float4*)(t + (size_t)(k0+kr)*512 + c0 + j);
      float vv[4] = {v.x*scl, v.y*scl, v.z*scl, v.w*scl};
      #pragma unroll
      for (int e=0;e<4;e++){
        unsigned short hs = f2bs(vv[e]);
        uh[swz32(j+e, kr)] = hs;
        ul[swz32(j+e, kr)] = f2bs(vv[e] - bs2f(hs));
      }
    }
    __syncthreads();
    {
      int kf = quad*8;
      v8s ah = *(const v8s*)&Bh[swz32(16*w + n, kf)];
      v8s al = *(const v8s*)&Bl[swz32(16*w + n, kf)];
      #pragma unroll
      for (int j=0;j<8;j++){
        v8s bh = *(const v8s*)&uh[swz32(j*16 + n, kf)];
        v8s bl = *(const v8s*)&ul[swz32(j*16 + n, kf)];
        acc[j] = __builtin_amdgcn_mfma_f32_16x16x32_bf16(ah, bh, acc[j], 0,0,0);
        acc[j] = __builtin_amdgcn_mfma_f32_16x16x32_bf16(ah, bl, acc[j], 0,0,0);
        acc[j] = __builtin_amdgcn_mfma_f32_16x16x32_bf16(al, bh, acc[j], 0,0,0);
      }
    }
  }
  // epilogue: two 64-row halves staged fp32, coalesced float4 in-place update
  const float CA = 3.4445f;
  __syncthreads();
  #pragma unroll
  for (int half=0; half<2; half++){
    if ((w>>2)==half){
      int rbase = (w&3)*16 + quad*4;
      #pragma unroll
      for (int j=0;j<8;j++)
        #pragma unroll
        for (int r=0;r<4;r++)
          Zs[(rbase+r)*128 + j*16 + n] = acc[j][r];
    }
    __syncthreads();
    for (int it=0; it<4; it++){
      int idx = it*2048 + tid*4;
      int i = idx>>7, jj = idx&127;
      float* dst = t + (size_t)(half*64 + i)*512 + c0 + jj;
      float4 told = *(const float4*)dst;
      float4 o;
      o.x = CA*(told.x*scl) + Zs[i*128+jj+0];
      o.y = CA*(told.y*scl) + Zs[i*128+jj+1];
      o.z = CA*(told.z*scl) + Zs[i*128+jj+2];
      o.w = CA*(told.w*scl) + Zs[i*128+jj+3];
      *(float4*)dst = o;
    }
    __syncthreads();
  }
}

// ---------------- momentum + decay scans (float4/thread, prefetch), per (b,h) strand ----------------
__global__ __launch_bounds__(256) void k_scan_mat(float* __restrict__ G, const float* __restrict__ mw,
    const float* __restrict__ MOMb, const float* __restrict__ DECb, int transposed){
  int bh = blockIdx.x>>6;
  int eblk = blockIdx.x&63;
  int e = (eblk*256 + threadIdx.x)*4;
  int h = bh&3;
  float4 u;
  if (transposed){
    int d = e>>9; int j = e&511;
    u.x = mw[(size_t)h*65536 + (size_t)(j+0)*128 + d];
    u.y = mw[(size_t)h*65536 + (size_t)(j+1)*128 + d];
    u.z = mw[(size_t)h*65536 + (size_t)(j+2)*128 + d];
    u.w = mw[(size_t)h*65536 + (size_t)(j+3)*128 + d];
  } else {
    u = *(const float4*)(mw + (size_t)h*65536 + e);
  }
  float4 mval = {0,0,0,0};
  size_t base = (size_t)(bh*32)*65536 + e;
  float4 s = *(const float4*)(G + base);
  for (int ci=0; ci<32; ci++){
    size_t off = base + (size_t)ci*65536;
    float4 s_next;
    if (ci<31) s_next = *(const float4*)(G + off + 65536);
    float mo = MOMb[bh*32+ci], de = DECb[bh*32+ci];
    float om = 1.0f-de;
    mval.x = mo*mval.x + s.x; mval.y = mo*mval.y + s.y;
    mval.z = mo*mval.z + s.z; mval.w = mo*mval.w + s.w;
    u.x = om*u.x + mval.x; u.y = om*u.y + mval.y;
    u.z = om*u.z + mval.z; u.w = om*u.w + mval.w;
    *(float4*)(G + off) = u;
    s = s_next;
  }
}

__global__ __launch_bounds__(128) void k_scan_gamma(float* __restrict__ GG, const float* __restrict__ mg,
    const float* __restrict__ MOMb, const float* __restrict__ DECb){
  int bh=blockIdx.x; int e=threadIdx.x; int h=bh&3;
  float u = mg[h*128+e]; float mval=0;
  for (int ci=0;ci<32;ci++){
    size_t off = ((size_t)(bh*32+ci))*128 + e;
    float s = GG[off];
    float mo = MOMb[bh*32+ci], de = DECb[bh*32+ci];
    mval = mo*mval + s;
    u = (1.0f-de)*u + mval;
    GG[off]=u;
  }
}

// ---------------- retrieval (MFMA, 512 thr, 4x2 wave grid) ----------------
__global__ __launch_bounds__(512) void k_retr(const float* __restrict__ Qb, const float* __restrict__ G1,
   const float* __restrict__ G2T, const float* __restrict__ GG, const float* __restrict__ mw1,
   const float* __restrict__ mw2, const float* __restrict__ mgamma,
   const float* __restrict__ GATEb, float* __restrict__ OUTT){
  int inst = blockIdx.x;
  int ci = inst & 31, h = (inst>>5)&3, b = inst>>7;
  size_t tok0 = (size_t)b*NN_ + (size_t)ci*64;
  int tid = threadIdx.x, w = tid>>6, lane = tid&63, n_l = lane&15, quad = lane>>4;
  int wm = w&3, wn = w>>2;
  __shared__ unsigned short xh[8192];
  __shared__ unsigned short wbh[8192], wbl[8192];
  __shared__ unsigned short ash[4096], asl[4096];
  const int first = (ci==0);
  const float* w1 = first ? (mw1 + (size_t)h*65536) : (G1 + (size_t)(inst-1)*65536);
  const float* w2j = mw2 + (size_t)h*65536;
  const float* w2d = G2T + (size_t)(inst-1)*65536;
  for (int it=0; it<4; it++){
    int idx = it*2048 + tid*4;
    int r = idx>>7, d = idx&127;
    float4 v = *(const float4*)(Qb + (tok0+r)*512 + h*128 + d);
    int p = swz(r,d);
    *(unsigned*)&xh[p]   = (unsigned)f2bs(v.x)|((unsigned)f2bs(v.y)<<16);
    *(unsigned*)&xh[p+2] = (unsigned)f2bs(v.z)|((unsigned)f2bs(v.w)<<16);
  }
  v4f acc2[4];
  #pragma unroll
  for (int j=0;j<4;j++){ v4f z={0.f,0.f,0.f,0.f}; acc2[j]=z; }
  for (int jt=0; jt<8; jt++){
    int j0 = jt*64;
    __syncthreads();
    for (int it=0; it<4; it++){
      int idx = it*2048 + tid*4;
      int d = idx>>6, jj = idx&63;
      float4 v = *(const float4*)(w1 + (size_t)d*512 + j0 + jj);
      unsigned short hh,ll;
      hilo(v.x,hh,ll); wbh[swz(jj+0,d)]=hh; wbl[swz(jj+0,d)]=ll;
      hilo(v.y,hh,ll); wbh[swz(jj+1,d)]=hh; wbl[swz(jj+1,d)]=ll;
      hilo(v.z,hh,ll); wbh[swz(jj+2,d)]=hh; wbl[swz(jj+2,d)]=ll;
      hilo(v.w,hh,ll); wbh[swz(jj+3,d)]=hh; wbl[swz(jj+3,d)]=ll;
    }
    __syncthreads();
    v4f acc1[2];
    #pragma unroll
    for (int nt=0; nt<2; nt++){ v4f z={0.f,0.f,0.f,0.f}; acc1[nt]=z; }
    #pragma unroll
    for (int ks=0; ks<4; ks++){
      int kf = ks*32 + quad*8;
      v8s av = *(const v8s*)&xh[swz(16*wm + n_l, kf)];
      #pragma unroll
      for (int nt=0; nt<2; nt++){
        int jj = wn*32 + nt*16 + n_l;
        v8s bh = *(const v8s*)&wbh[swz(jj, kf)];
        v8s bl = *(const v8s*)&wbl[swz(jj, kf)];
        acc1[nt] = __builtin_amdgcn_mfma_f32_16x16x32_bf16(av, bh, acc1[nt], 0,0,0);
        acc1[nt] = __builtin_amdgcn_mfma_f32_16x16x32_bf16(av, bl, acc1[nt], 0,0,0);
      }
    }
    #pragma unroll
    for (int nt=0; nt<2; nt++)
      #pragma unroll
      for (int r=0;r<4;r++){
        int t = 16*wm + quad*4 + r;
        int jj = wn*32 + nt*16 + n_l;
        float g = geluf(acc1[nt][r]);
        unsigned short gh = f2bs(g);
        ash[swz64(t, jj)] = gh;
        asl[swz64(t, jj)] = f2bs(g - bs2f(gh));
      }
    __syncthreads();
    if (first){
      for (int it=0; it<4; it++){
        int idx = it*2048 + tid*4;
        int jj = idx>>7, d = idx&127;
        float4 v = *(const float4*)(w2j + (size_t)(j0+jj)*128 + d);
        unsigned short hh,ll;
        hilo(v.x,hh,ll); wbh[swz64(d+0,jj)]=hh; wbl[swz64(d+0,jj)]=ll;
        hilo(v.y,hh,ll); wbh[swz64(d+1,jj)]=hh; wbl[swz64(d+1,jj)]=ll;
        hilo(v.z,hh,ll); wbh[swz64(d+2,jj)]=hh; wbl[swz64(d+2,jj)]=ll;
        hilo(v.w,hh,ll); wbh[swz64(d+3,jj)]=hh; wbl[swz64(d+3,jj)]=ll;
      }
    } else {
      for (int it=0; it<4; it++){
        int idx = it*2048 + tid*4;
        int d = idx>>6, jj = idx&63;
        float4 v = *(const float4*)(w2d + (size_t)d*512 + j0 + jj);
        unsigned short h0,h1,h2,h3,l0,l1,l2,l3;
        hilo(v.x,h0,l0); hilo(v.y,h1,l1); hilo(v.z,h2,l2); hilo(v.w,h3,l3);
        int p = swz64(d,jj);
        *(unsigned*)&wbh[p]   = (unsigned)h0|((unsigned)h1<<16);
        *(unsigned*)&wbh[p+2] = (unsigned)h2|((unsigned)h3<<16);
        *(unsigned*)&wbl[p]   = (unsigned)l0|((unsigned)l1<<16);
        *(unsigned*)&wbl[p+2] = (unsigned)l2|((unsigned)l3<<16);
      }
    }
    __syncthreads();
    #pragma unroll
    for (int ks=0; ks<2; ks++){
      int kf = ks*32 + quad*8;
      v8s ah = *(const v8s*)&ash[swz64(16*wm + n_l, kf)];
      v8s al = *(const v8s*)&asl[swz64(16*wm + n_l, kf)];
      #pragma unroll
      for (int nt=0; nt<4; nt++){
        int dc = wn*64 + nt*16 + n_l;
        v8s bh = *(const v8s*)&wbh[swz64(dc, kf)];
        v8s bl = *(const v8s*)&wbl[swz64(dc, kf)];
        acc2[nt] = __builtin_amdgcn_mfma_f32_16x16x32_bf16(ah, bh, acc2[nt], 0,0,0);
        acc2[nt] = __builtin_amdgcn_mfma_f32_16x16x32_bf16(ah, bl, acc2[nt], 0,0,0);
        acc2[nt] = __builtin_amdgcn_mfma_f32_16x16x32_bf16(al, bh, acc2[nt], 0,0,0);
      }
    }
  }
  float* red = (float*)wbh;   // [0..127]: ssh[2][64]
  __syncthreads();
  float ss[4] = {0,0,0,0};
  #pragma unroll
  for (int nt=0; nt<4; nt++)
    #pragma unroll
    for (int r=0;r<4;r++) ss[r] += acc2[nt][r]*acc2[nt][r];
  #pragma unroll
  for (int m=1;m<16;m<<=1)
    #pragma unroll
    for (int r=0;r<4;r++) ss[r] += __shfl_xor(ss[r], m, 64);
  if (n_l==0){
    #pragma unroll
    for (int r=0;r<4;r++) red[wn*64 + 16*wm + quad*4 + r] = ss[r];
  }
  __syncthreads();
  float rr[4];
  #pragma unroll
  for (int r=0;r<4;r++){
    int row = 16*wm + quad*4 + r;
    float tot = red[row] + red[64 + row];
    rr[r] = rsqrtf(tot*(1.0f/128.0f) + 1e-6f);
  }
  float gv[4];
  #pragma unroll
  for (int nt=0; nt<4; nt++){
    int d = wn*64 + nt*16 + n_l;
    gv[nt] = first ? mgamma[h*128+d] : GG[(size_t)(inst-1)*128+d];
  }
  float gate[4];
  #pragma unroll
  for (int r=0;r<4;r++) gate[r] = GATEb[(tok0 + 16*wm + quad*4 + r)*4 + h];
  #pragma unroll
  for (int nt=0; nt<4; nt++)
    #pragma unroll
    for (int r=0;r<4;r++){
      int t = 16*wm + quad*4 + r;
      int d = wn*64 + nt*16 + n_l;
      float qv = Qb[(tok0+t)*512 + h*128 + d];
      OUTT[(tok0+t)*512 + h*128 + d] = (acc2[nt][r]*rr[r]*gv[nt] + qv)*gate[r];
    }
}

extern "C" void kernel_launch(void* const* d_in, const int* in_sizes, int n_in,
                              void* d_out, int out_size, void* d_ws, size_t ws_size,
                              hipStream_t stream) {
  (void)in_sizes; (void)n_in; (void)out_size; (void)ws_size;
  const float* seq   = (const float*)d_in[0];
  const float* sg    = (const float*)d_in[1];
  const float* rg    = (const float*)d_in[2];
  const float* Wq    = (const float*)d_in[3];
  const float* Wk    = (const float*)d_in[4];
  const float* Wv    = (const float*)d_in[5];
  const float* Wlr   = (const float*)d_in[6];
  const float* blr   = (const float*)d_in[7];
  const float* Wm    = (const float*)d_in[8];
  const float* bm    = (const float*)d_in[9];
  const float* Wd    = (const float*)d_in[10];
  const float* bd    = (const float*)d_in[11];
  const float* Wgate = (const float*)d_in[12];
  const float* Wc    = (const float*)d_in[13];
  const float* mw1   = (const float*)d_in[14];
  const float* mw2   = (const float*)d_in[15];
  const float* mgam  = (const float*)d_in[16];

  float* W = (float*)d_ws;
  float* S    = W + 0;
  float* SR   = W + 2097152;
  float* Kb   = W + 4194304;
  float* Vb   = W + 6291456;
  float* H1T  = W + 8388608;
  float* DH2  = W + 16777216;
  float* Qb   = W + 18874368;
  float* LRb  = W + 20971520;
  float* GATEb= W + 20987904;
  float* MOMb = W + 21004288;
  float* DECb = W + 21004544;
  float* GGb  = W + 21004800;
  float* G1   = W + 21037568;
  float* G2T  = W + 37814784;
  float* NRM2 = W + 54592000;   // 512 floats
  unsigned short* ABh = (unsigned short*)(W + 0);        // overlay S+SR (dead by NS time)
  unsigned short* ABl = (unsigned short*)(W + 4194304);  // overlay Kb+Vb (dead after k_dw1)
  float* OUTT = W + 8388608;  // overlay H1T slot (free by retrieval time)

  k_rmsnorm<<<4096,256,0,stream>>>(seq, sg, rg, S, SR);
  dim3 gg(64,4);
  k_gemm_mfma<<<gg,256,0,stream>>>(S,  Wk, Kb);
  k_gemm_mfma<<<gg,256,0,stream>>>(S,  Wv, Vb);
  k_gemm_mfma<<<gg,256,0,stream>>>(SR, Wq, Qb);
  k_small<<<64,256,0,stream>>>(S, SR, Wlr, blr, Wm, bm, Wd, bd, Wgate, LRb, GATEb, MOMb, DECb);
  k_fwd<<<256,512,0,stream>>>(Kb, Vb, LRb, mw1, mw2, mgam, H1T, DH2, GGb);
  k_dw2<<<256,512,0,stream>>>(DH2, H1T, G2T, NRM2);
  k_dw1<<<256,512,0,stream>>>(Kb, DH2, H1T, mw2, G1, NRM2);
  for (int it=0; it<5; it++){
    k_nsAB<<<512,512,0,stream>>>(G1, G2T, NRM2, ABh, ABl, it==0);
    k_nsZ<<<2048,512,0,stream>>>(G1, G2T, ABh, ABl, NRM2, it==0);
  }
  k_scan_mat<<<512,256,0,stream>>>(G1,  mw1, MOMb, DECb, 0);
  k_scan_mat<<<512,256,0,stream>>>(G2T, mw2, MOMb, DECb, 1);
  k_scan_gamma<<<8,128,0,stream>>>(GGb, mgam, MOMb, DECb);
  k_retr<<<256,512,0,stream>>>(Qb, G1, G2T, GGb, mw1, mw2, mgam, GATEb, OUTT);
  k_gemm_mfma<<<gg,256,0,stream>>>(OUTT, Wc, (float*)d_out);
}

// Round 12
// 1064.634 us; speedup vs baseline: 1.1253x; 1.1253x over previous
//
#include <hip/hip_runtime.h>
#include <hip/hip_bf16.h>
#include <math.h>

#define NN_ 2048

typedef short v8s __attribute__((ext_vector_type(8)));
typedef float v4f __attribute__((ext_vector_type(4)));

__device__ __forceinline__ float geluf(float x){ return 0.5f*x*(1.0f+erff(x*0.70710678118654752440f)); }
__device__ __forceinline__ float gelupf(float x){
  float cdf = 0.5f*(1.0f+erff(x*0.70710678118654752440f));
  float pdf = 0.39894228040143267794f*expf(-0.5f*x*x);
  return cdf + x*pdf;
}
__device__ __forceinline__ float sigm(float x){ return 1.0f/(1.0f+expf(-x)); }

__device__ __forceinline__ unsigned short f2bs(float f){
  __hip_bfloat16 h = __float2bfloat16(f);
  return __builtin_bit_cast(unsigned short, h);
}
__device__ __forceinline__ float bs2f(unsigned short u){
  unsigned v = ((unsigned)u)<<16;
  return __builtin_bit_cast(float, v);
}
__device__ __forceinline__ void hilo(float v, unsigned short &h, unsigned short &l){
  h = f2bs(v); l = f2bs(v - bs2f(h));
}
// XOR swizzle folding (r>>2): transpose-staging writes spread across bank groups
__device__ __forceinline__ int swz(int r, int k){
  return r*128 + ((((k>>3) ^ (r&15) ^ ((r>>2)&15)) & 15)<<3) + (k&7);
}
__device__ __forceinline__ int swz64(int r, int k){
  return r*64 + ((((k>>3) ^ (r&7) ^ ((r>>2)&7)) & 7)<<3) + (k&7);
}

// ---------------- rmsnorm of seq with store/retrieve gains ----------------
__global__ __launch_bounds__(256) void k_rmsnorm(const float* __restrict__ seq, const float* __restrict__ gs,
                          const float* __restrict__ gr, float* __restrict__ S, float* __restrict__ SR){
  int tok = blockIdx.x;
  const float* row = seq + (size_t)tok*512;
  int tid = threadIdx.x;
  float x0 = row[tid];
  float x1 = row[tid+256];
  float ss = x0*x0 + x1*x1;
  #pragma unroll
  for (int o=32;o>0;o>>=1) ss += __shfl_down(ss, o, 64);
  __shared__ float wsum[4];
  int wid = tid>>6, lid = tid&63;
  if (lid==0) wsum[wid]=ss;
  __syncthreads();
  float tot = wsum[0]+wsum[1]+wsum[2]+wsum[3];
  float r = rsqrtf(tot*(1.0f/512.0f) + 1e-6f);
  size_t o0 = (size_t)tok*512 + tid;
  S[o0]      = x0*r*gs[tid];
  S[o0+256]  = x1*r*gs[tid+256];
  SR[o0]     = x0*r*gr[tid];
  SR[o0+256] = x1*r*gr[tid+256];
}

// ---------------- MFMA GEMM: O[4096x512] = X @ Wt, hi/lo, 64x128 tiles ----------------
__global__ __launch_bounds__(256) void k_gemm_mfma(const float* __restrict__ X, const float* __restrict__ Wt,
                                                   float* __restrict__ O){
  int m0 = blockIdx.x*64, n0 = blockIdx.y*128;
  __shared__ unsigned short Xh[4096], Xl[4096], Wh[8192], Wl[8192];
  int tid = threadIdx.x, w = tid>>6, lane = tid&63, n_l = lane&15, quad = lane>>4;
  v4f acc[8];
  #pragma unroll
  for (int j=0;j<8;j++){ v4f z={0.f,0.f,0.f,0.f}; acc[j]=z; }
  for (int kc=0; kc<8; kc++){
    int k0 = kc*64;
    __syncthreads();
    for (int it=0; it<4; it++){
      int idx = it*1024 + tid*4;
      int r = idx>>6, k = idx&63;
      float4 v = *(const float4*)(X + (size_t)(m0+r)*512 + k0 + k);
      union { unsigned long long q; unsigned short s[4]; } uh, ul;
      hilo(v.x,uh.s[0],ul.s[0]); hilo(v.y,uh.s[1],ul.s[1]);
      hilo(v.z,uh.s[2],ul.s[2]); hilo(v.w,uh.s[3],ul.s[3]);
      int p = swz64(r,k);
      *(unsigned long long*)&Xh[p] = uh.q;
      *(unsigned long long*)&Xl[p] = ul.q;
    }
    for (int it=0; it<8; it++){
      int idx = it*1024 + tid*4;
      int k = idx>>7, n = idx&127;
      float4 v = *(const float4*)(Wt + (size_t)(k0+k)*512 + n0 + n);
      unsigned short hh,ll;
      hilo(v.x,hh,ll); Wh[swz64(n+0,k)]=hh; Wl[swz64(n+0,k)]=ll;
      hilo(v.y,hh,ll); Wh[swz64(n+1,k)]=hh; Wl[swz64(n+1,k)]=ll;
      hilo(v.z,hh,ll); Wh[swz64(n+2,k)]=hh; Wl[swz64(n+2,k)]=ll;
      hilo(v.w,hh,ll); Wh[swz64(n+3,k)]=hh; Wl[swz64(n+3,k)]=ll;
    }
    __syncthreads();
    #pragma unroll
    for (int ks=0; ks<2; ks++){
      int kf = ks*32 + quad*8;
      v8s ah = *(const v8s*)&Xh[swz64(16*w + n_l, kf)];
      v8s al = *(const v8s*)&Xl[swz64(16*w + n_l, kf)];
      #pragma unroll
      for (int nt=0; nt<8; nt++){
        v8s bh = *(const v8s*)&Wh[swz64(nt*16+n_l, kf)];
        v8s bl = *(const v8s*)&Wl[swz64(nt*16+n_l, kf)];
        acc[nt] = __builtin_amdgcn_mfma_f32_16x16x32_bf16(ah, bh, acc[nt], 0,0,0);
        acc[nt] = __builtin_amdgcn_mfma_f32_16x16x32_bf16(ah, bl, acc[nt], 0,0,0);
        acc[nt] = __builtin_amdgcn_mfma_f32_16x16x32_bf16(al, bh, acc[nt], 0,0,0);
      }
    }
  }
  #pragma unroll
  for (int nt=0; nt<8; nt++)
    #pragma unroll
    for (int r=0;r<4;r++)
      O[(size_t)(m0 + 16*w + quad*4 + r)*512 + n0 + nt*16 + n_l] = acc[nt][r];
}

// ---------------- lr/gate per token, pooled->mom/dec per chunk ----------------
__global__ __launch_bounds__(256) void k_small(const float* __restrict__ S, const float* __restrict__ SR,
    const float* __restrict__ Wlr, const float* __restrict__ blr, const float* __restrict__ Wm,
    const float* __restrict__ bm, const float* __restrict__ Wd, const float* __restrict__ bd,
    const float* __restrict__ Wgate,
    float* __restrict__ LRb, float* __restrict__ GATEb, float* __restrict__ MOMb, float* __restrict__ DECb){
  int bc = blockIdx.x;            // b*32 + ci
  int b = bc>>5, ci = bc&31;
  int tid = threadIdx.x;
  int t = tid>>2, h = tid&3;
  size_t tokbase = (size_t)b*NN_ + (size_t)ci*64;
  __shared__ float pool[512];
  for (int c=tid; c<512; c+=256){
    float s=0;
    for (int t2=0;t2<64;t2++) s += S[(tokbase+t2)*512 + c];
    pool[c] = s*(1.0f/64.0f);
  }
  size_t tok = tokbase + t;
  const float* srow = S + tok*512;
  const float* srrow = SR + tok*512;
  float accl=0, accg=0;
  for (int d=0; d<512; d++){
    accl += srow[d]*Wlr[d*4+h];
    accg += srrow[d]*Wgate[d*4+h];
  }
  accl += blr[h];
  LRb[tok*4+h] = sigm(accl);
  GATEb[tok*4+h] = sigm(accg);
  __syncthreads();
  if (tid<8){
    int hh = tid&3, which = tid>>2;
    float a=0;
    const float* Wx = which? Wd : Wm;
    for (int d=0; d<512; d++) a += pool[d]*Wx[d*4+hh];
    a += which? bd[hh] : bm[hh];
    float v = sigm(a);
    size_t o = ((size_t)b*4+hh)*32 + ci;
    if (which) DECb[o]=v; else MOMb[o]=v;
  }
}

// ---------------- fused memory-MLP forward + rmsnorm backward (MFMA, 512 thr, 4x2 wave grid) ----------------
__global__ __launch_bounds__(512) void k_fwd(const float* __restrict__ Kb, const float* __restrict__ Vb,
    const float* __restrict__ LRb, const float* __restrict__ mw1, const float* __restrict__ mw2,
    const float* __restrict__ mgamma, float* __restrict__ H1T, float* __restrict__ DH2,
    float* __restrict__ GG){
  int inst = blockIdx.x;
  int ci = inst & 31, h = (inst>>5)&3, b = inst>>7;
  size_t tok0 = (size_t)b*NN_ + (size_t)ci*64;
  int tid = threadIdx.x, w = tid>>6, lane = tid&63, n_l = lane&15, quad = lane>>4;
  int wm = w&3, wn = w>>2;          // wm: token-quarter (16 rows), wn: N-half
  __shared__ unsigned short xh[8192];              // [64 t][128 d] swz, hi only
  __shared__ unsigned short wbh[8192], wbl[8192];  // weight tile
  __shared__ unsigned short ash[4096], asl[4096];  // gelu(h1) tile [64 t][64 j] swz64
  const float* w1 = mw1 + (size_t)h*65536;  // [128 d][512 j]
  const float* w2 = mw2 + (size_t)h*65536;  // [512 j][128 d]
  for (int it=0; it<4; it++){
    int idx = it*2048 + tid*4;
    int r = idx>>7, d = idx&127;
    float4 v = *(const float4*)(Kb + (tok0+r)*512 + h*128 + d);
    int p = swz(r,d);
    *(unsigned*)&xh[p]   = (unsigned)f2bs(v.x)|((unsigned)f2bs(v.y)<<16);
    *(unsigned*)&xh[p+2] = (unsigned)f2bs(v.z)|((unsigned)f2bs(v.w)<<16);
  }
  v4f acc2[4];
  #pragma unroll
  for (int j=0;j<4;j++){ v4f z={0.f,0.f,0.f,0.f}; acc2[j]=z; }
  for (int jt=0; jt<8; jt++){
    int j0 = jt*64;
    __syncthreads();
    for (int it=0; it<4; it++){
      int idx = it*2048 + tid*4;
      int d = idx>>6, jj = idx&63;
      float4 v = *(const float4*)(w1 + (size_t)d*512 + j0 + jj);
      unsigned short hh,ll;
      hilo(v.x,hh,ll); wbh[swz(jj+0,d)]=hh; wbl[swz(jj+0,d)]=ll;
      hilo(v.y,hh,ll); wbh[swz(jj+1,d)]=hh; wbl[swz(jj+1,d)]=ll;
      hilo(v.z,hh,ll); wbh[swz(jj+2,d)]=hh; wbl[swz(jj+2,d)]=ll;
      hilo(v.w,hh,ll); wbh[swz(jj+3,d)]=hh; wbl[swz(jj+3,d)]=ll;
    }
    __syncthreads();
    v4f acc1[2];
    #pragma unroll
    for (int nt=0; nt<2; nt++){ v4f z={0.f,0.f,0.f,0.f}; acc1[nt]=z; }
    #pragma unroll
    for (int ks=0; ks<4; ks++){
      int kf = ks*32 + quad*8;
      v8s av = *(const v8s*)&xh[swz(16*wm + n_l, kf)];
      #pragma unroll
      for (int nt=0; nt<2; nt++){
        int jj = wn*32 + nt*16 + n_l;
        v8s bh = *(const v8s*)&wbh[swz(jj, kf)];
        v8s bl = *(const v8s*)&wbl[swz(jj, kf)];
        acc1[nt] = __builtin_amdgcn_mfma_f32_16x16x32_bf16(av, bh, acc1[nt], 0,0,0);
        acc1[nt] = __builtin_amdgcn_mfma_f32_16x16x32_bf16(av, bl, acc1[nt], 0,0,0);
      }
    }
    #pragma unroll
    for (int nt=0; nt<2; nt++){
      int jj = wn*32 + nt*16 + n_l;
      float4 hv4;
      hv4.x = acc1[nt][0]; hv4.y = acc1[nt][1]; hv4.z = acc1[nt][2]; hv4.w = acc1[nt][3];
      *(float4*)(H1T + (size_t)inst*32768 + (size_t)(j0+jj)*64 + 16*wm + quad*4) = hv4;
      #pragma unroll
      for (int r=0;r<4;r++){
        int t = 16*wm + quad*4 + r;
        float g = geluf(acc1[nt][r]);
        unsigned short gh = f2bs(g);
        ash[swz64(t, jj)] = gh;
        asl[swz64(t, jj)] = f2bs(g - bs2f(gh));
      }
    }
    __syncthreads();
    for (int it=0; it<4; it++){
      int idx = it*2048 + tid*4;
      int jj = idx>>7, d = idx&127;
      float4 v = *(const float4*)(w2 + (size_t)(j0+jj)*128 + d);
      unsigned short hh,ll;
      hilo(v.x,hh,ll); wbh[swz64(d+0,jj)]=hh; wbl[swz64(d+0,jj)]=ll;
      hilo(v.y,hh,ll); wbh[swz64(d+1,jj)]=hh; wbl[swz64(d+1,jj)]=ll;
      hilo(v.z,hh,ll); wbh[swz64(d+2,jj)]=hh; wbl[swz64(d+2,jj)]=ll;
      hilo(v.w,hh,ll); wbh[swz64(d+3,jj)]=hh; wbl[swz64(d+3,jj)]=ll;
    }
    __syncthreads();
    #pragma unroll
    for (int ks=0; ks<2; ks++){
      int kf = ks*32 + quad*8;
      v8s ah = *(const v8s*)&ash[swz64(16*wm + n_l, kf)];
      v8s al = *(const v8s*)&asl[swz64(16*wm + n_l, kf)];
      #pragma unroll
      for (int nt=0; nt<4; nt++){
        int dc = wn*64 + nt*16 + n_l;
        v8s bh = *(const v8s*)&wbh[swz64(dc, kf)];
        v8s bl = *(const v8s*)&wbl[swz64(dc, kf)];
        acc2[nt] = __builtin_amdgcn_mfma_f32_16x16x32_bf16(ah, bh, acc2[nt], 0,0,0);
        acc2[nt] = __builtin_amdgcn_mfma_f32_16x16x32_bf16(ah, bl, acc2[nt], 0,0,0);
        acc2[nt] = __builtin_amdgcn_mfma_f32_16x16x32_bf16(al, bh, acc2[nt], 0,0,0);
      }
    }
  }
  // epilogue: rmsnorm backward; rows split over wm, cols split over wn
  float* red = (float*)wbh;   // [0..127] sgg, [128..255] ssh[2][64], [256..383] doth[2][64]
  __syncthreads();
  if (tid<128) red[tid]=0.0f;
  float ss[4] = {0,0,0,0};
  #pragma unroll
  for (int nt=0; nt<4; nt++)
    #pragma unroll
    for (int r=0;r<4;r++) ss[r] += acc2[nt][r]*acc2[nt][r];
  #pragma unroll
  for (int m=1;m<16;m<<=1)
    #pragma unroll
    for (int r=0;r<4;r++) ss[r] += __shfl_xor(ss[r], m, 64);
  if (n_l==0){
    #pragma unroll
    for (int r=0;r<4;r++) red[128 + wn*64 + 16*wm + quad*4 + r] = ss[r];
  }
  __syncthreads();
  float rr[4];
  #pragma unroll
  for (int r=0;r<4;r++){
    int row = 16*wm + quad*4 + r;
    float tot = red[128 + row] + red[128 + 64 + row];
    rr[r] = rsqrtf(tot*(1.0f/128.0f) + 1e-6f);
  }
  float gv[4];
  #pragma unroll
  for (int nt=0; nt<4; nt++) gv[nt] = mgamma[h*128 + wn*64 + nt*16 + n_l];
  float lrv[4];
  #pragma unroll
  for (int r=0;r<4;r++) lrv[r] = LRb[(tok0 + 16*wm + quad*4 + r)*4 + h]*(2.0f/128.0f);
  float dnv[4][4]; float dot[4]={0,0,0,0}; float ggp[4];
  #pragma unroll
  for (int nt=0; nt<4; nt++) ggp[nt]=0.0f;
  #pragma unroll
  for (int nt=0; nt<4; nt++)
    #pragma unroll
    for (int r=0;r<4;r++){
      int t = 16*wm + quad*4 + r;
      int d = wn*64 + nt*16 + n_l;
      float xv = Kb[(tok0+t)*512 + h*128 + d];
      float vv = Vb[(tok0+t)*512 + h*128 + d];
      float nval = acc2[nt][r]*rr[r];
      float pred = nval*gv[nt] + xv;
      float dp = lrv[r]*(pred - vv);
      ggp[nt] += dp*nval;
      float dn = dp*gv[nt];
      dnv[nt][r] = dn;
      dot[r] += dn*acc2[nt][r];
    }
  #pragma unroll
  for (int nt=0; nt<4; nt++) atomicAdd(&red[wn*64 + nt*16 + n_l], ggp[nt]);
  #pragma unroll
  for (int m=1;m<16;m<<=1)
    #pragma unroll
    for (int r=0;r<4;r++) dot[r] += __shfl_xor(dot[r], m, 64);
  if (n_l==0){
    #pragma unroll
    for (int r=0;r<4;r++) red[256 + wn*64 + 16*wm + quad*4 + r] = dot[r];
  }
  __syncthreads();
  #pragma unroll
  for (int r=0;r<4;r++){
    int row = 16*wm + quad*4 + r;
    float dtot = red[256 + row] + red[256 + 64 + row];
    float dt = dtot*rr[r]*rr[r]*rr[r]*(1.0f/128.0f);
    #pragma unroll
    for (int nt=0; nt<4; nt++){
      int d = wn*64 + nt*16 + n_l;
      DH2[(size_t)inst*8192 + (size_t)row*128 + d] = rr[r]*dnv[nt][r] - dt*acc2[nt][r];
    }
  }
  __syncthreads();
  if (tid<128) GG[(size_t)inst*128+tid] = -red[tid];
}

// ---------------- dw2 (MFMA, 512 thr): G2T[d][j] = -sum_t dh2[t,d]*gelu(h1[t,j]); norm2[256+inst] ----------------
__global__ __launch_bounds__(512) void k_dw2(const float* __restrict__ DH2, const float* __restrict__ H1T,
                                             float* __restrict__ G2T, float* __restrict__ norm2){
  int inst = blockIdx.x;
  int tid = threadIdx.x, w = tid>>6, lane = tid&63, n_l = lane&15, quad = lane>>4;
  __shared__ unsigned short d2h[8192], d2l[8192];  // dh2^T [128 d][64 t] swz64 hi/lo
  __shared__ unsigned short ath[8192], atl[8192];  // gelu(h1)^T tile [128 j][64 t] swz64 hi/lo
  float nrm = 0.0f;
  for (int it=0; it<4; it++){
    int idx = it*2048 + tid*4;
    int t = idx>>7, d = idx&127;
    float4 v = *(const float4*)(DH2 + (size_t)inst*8192 + idx);
    unsigned short hh,ll;
    hilo(v.x,hh,ll); d2h[swz64(d+0,t)]=hh; d2l[swz64(d+0,t)]=ll;
    hilo(v.y,hh,ll); d2h[swz64(d+1,t)]=hh; d2l[swz64(d+1,t)]=ll;
    hilo(v.z,hh,ll); d2h[swz64(d+2,t)]=hh; d2l[swz64(d+2,t)]=ll;
    hilo(v.w,hh,ll); d2h[swz64(d+3,t)]=hh; d2l[swz64(d+3,t)]=ll;
  }
  for (int jt=0; jt<4; jt++){
    int j0 = jt*128;
    if (jt) __syncthreads();
    for (int it=0; it<4; it++){
      int idx = it*2048 + tid*4;
      int j = idx>>6, t = idx&63;
      float4 v = *(const float4*)(H1T + (size_t)inst*32768 + (size_t)(j0+j)*64 + t);
      union { unsigned long long q; unsigned short s[4]; } uh, ul;
      float g0=geluf(v.x), g1=geluf(v.y), g2=geluf(v.z), g3=geluf(v.w);
      hilo(g0,uh.s[0],ul.s[0]); hilo(g1,uh.s[1],ul.s[1]);
      hilo(g2,uh.s[2],ul.s[2]); hilo(g3,uh.s[3],ul.s[3]);
      int p = swz64(j,t);
      *(unsigned long long*)&ath[p] = uh.q;
      *(unsigned long long*)&atl[p] = ul.q;
    }
    __syncthreads();
    v4f acc[8];
    #pragma unroll
    for (int j=0;j<8;j++){ v4f z={0.f,0.f,0.f,0.f}; acc[j]=z; }
    #pragma unroll
    for (int ks=0; ks<2; ks++){
      int kf = ks*32 + quad*8;
      v8s ah = *(const v8s*)&d2h[swz64(16*w + n_l, kf)];
      v8s al = *(const v8s*)&d2l[swz64(16*w + n_l, kf)];
      #pragma unroll
      for (int nt=0; nt<8; nt++){
        v8s bh = *(const v8s*)&ath[swz64(nt*16+n_l, kf)];
        v8s bl = *(const v8s*)&atl[swz64(nt*16+n_l, kf)];
        acc[nt] = __builtin_amdgcn_mfma_f32_16x16x32_bf16(ah, bh, acc[nt], 0,0,0);
        acc[nt] = __builtin_amdgcn_mfma_f32_16x16x32_bf16(ah, bl, acc[nt], 0,0,0);
        acc[nt] = __builtin_amdgcn_mfma_f32_16x16x32_bf16(al, bh, acc[nt], 0,0,0);
      }
    }
    #pragma unroll
    for (int nt=0; nt<8; nt++)
      #pragma unroll
      for (int r=0;r<4;r++){
        float gvv = acc[nt][r];
        nrm += gvv*gvv;
        G2T[(size_t)inst*65536 + (size_t)(16*w + quad*4 + r)*512 + j0 + nt*16 + n_l] = -gvv;
      }
  }
  #pragma unroll
  for (int o=32;o>0;o>>=1) nrm += __shfl_down(nrm, o, 64);
  __syncthreads();
  float* red8 = (float*)d2h;
  if (lane==0) red8[w]=nrm;
  __syncthreads();
  if (tid==0){
    float s=0;
    #pragma unroll
    for (int i=0;i<8;i++) s+=red8[i];
    norm2[256+inst] = s;
  }
}

// ---------------- dw1 (MFMA, 512 thr, fused): da^T = w2@dh2^T; dh1 = da*gelu'; G1 = -x^T@dh1 ----------------
__global__ __launch_bounds__(512) void k_dw1(const float* __restrict__ Kb, const float* __restrict__ DH2,
    const float* __restrict__ H1T, const float* __restrict__ mw2, float* __restrict__ G1,
    float* __restrict__ norm2){
  int inst = blockIdx.x;
  int ci = inst&31, h=(inst>>5)&3, b=inst>>7;
  size_t tok0 = (size_t)b*NN_ + (size_t)ci*64;
  int tid = threadIdx.x, w = tid>>6, lane = tid&63, n_l = lane&15, quad = lane>>4;
  int wm = w&3, wn = w>>2;
  __shared__ unsigned short dh2h[8192];   // dh2 [64 t][128 d] swz, hi
  __shared__ unsigned short xth[8192];    // x^T [128 d][64 t] swz64, hi
  __shared__ unsigned short wb[16384];    // w2 tile hi/lo; reused for dh1T hi/lo
  unsigned short* wbl = wb + 8192;
  unsigned short* d1h = wb;
  unsigned short* d1l = wb + 4096;
  const float* w2 = mw2 + (size_t)h*65536;
  float nrm = 0.0f;
  for (int it=0; it<4; it++){
    int idx = it*2048 + tid*4;
    int t = idx>>7, d = idx&127;
    float4 v = *(const float4*)(DH2 + (size_t)inst*8192 + idx);
    union { unsigned long long q; unsigned short s[4]; } uh;
    uh.s[0]=f2bs(v.x); uh.s[1]=f2bs(v.y); uh.s[2]=f2bs(v.z); uh.s[3]=f2bs(v.w);
    *(unsigned long long*)&dh2h[swz(t,d)] = uh.q;
  }
  for (int it=0; it<4; it++){
    int idx = it*2048 + tid*4;
    int t = idx>>7, d = idx&127;
    float4 v = *(const float4*)(Kb + (tok0+t)*512 + h*128 + d);
    xth[swz64(d+0,t)] = f2bs(v.x);
    xth[swz64(d+1,t)] = f2bs(v.y);
    xth[swz64(d+2,t)] = f2bs(v.z);
    xth[swz64(d+3,t)] = f2bs(v.w);
  }
  for (int jt=0; jt<8; jt++){
    int j0 = jt*64;
    __syncthreads();
    for (int it=0; it<4; it++){
      int idx = it*2048 + tid*4;
      int jj = idx>>7, d = idx&127;
      float4 v = *(const float4*)(w2 + (size_t)(j0+jj)*128 + d);
      union { unsigned long long q; unsigned short s[4]; } uh, ul;
      hilo(v.x,uh.s[0],ul.s[0]); hilo(v.y,uh.s[1],ul.s[1]);
      hilo(v.z,uh.s[2],ul.s[2]); hilo(v.w,uh.s[3],ul.s[3]);
      int p = swz(jj,d);
      *(unsigned long long*)&wb[p]  = uh.q;
      *(unsigned long long*)&wbl[p] = ul.q;
    }
    __syncthreads();
    // daT: wave (wm,wn): M j-row 16*wm; N t-tiles wn*32+{0,16}; K=128 d
    v4f da[2];
    #pragma unroll
    for (int nt=0; nt<2; nt++){ v4f z={0.f,0.f,0.f,0.f}; da[nt]=z; }
    #pragma unroll
    for (int ks=0; ks<4; ks++){
      int kf = ks*32 + quad*8;
      v8s a_h = *(const v8s*)&wb[swz(16*wm + n_l, kf)];
      v8s a_l = *(const v8s*)&wbl[swz(16*wm + n_l, kf)];
      #pragma unroll
      for (int nt=0; nt<2; nt++){
        v8s bv = *(const v8s*)&dh2h[swz(wn*32 + nt*16 + n_l, kf)];
        da[nt] = __builtin_amdgcn_mfma_f32_16x16x32_bf16(a_h, bv, da[nt], 0,0,0);
        da[nt] = __builtin_amdgcn_mfma_f32_16x16x32_bf16(a_l, bv, da[nt], 0,0,0);
      }
    }
    __syncthreads();
    // dh1T = daT * gelu'(h1T): wave covers (16 j) x (32 t)
    #pragma unroll
    for (int nt=0; nt<2; nt++)
      #pragma unroll
      for (int r=0;r<4;r++){
        int jl = 16*wm + quad*4 + r;
        int t = wn*32 + nt*16 + n_l;
        float hv = H1T[(size_t)inst*32768 + (size_t)(j0+jl)*64 + t];
        float d1 = da[nt][r]*gelupf(hv);
        unsigned short hs = f2bs(d1);
        d1h[swz64(jl,t)] = hs;
        d1l[swz64(jl,t)] = f2bs(d1 - bs2f(hs));
      }
    __syncthreads();
    // G1 tile: wave w: M d-row 16w; N=64 j (4 nt); K=64 t
    v4f g[4];
    #pragma unroll
    for (int nt=0; nt<4; nt++){ v4f z={0.f,0.f,0.f,0.f}; g[nt]=z; }
    #pragma unroll
    for (int ks=0; ks<2; ks++){
      int kf = ks*32 + quad*8;
      v8s a_ = *(const v8s*)&xth[swz64(16*w + n_l, kf)];
      #pragma unroll
      for (int nt=0; nt<4; nt++){
        v8s bh = *(const v8s*)&d1h[swz64(nt*16+n_l, kf)];
        v8s bl = *(const v8s*)&d1l[swz64(nt*16+n_l, kf)];
        g[nt] = __builtin_amdgcn_mfma_f32_16x16x32_bf16(a_, bh, g[nt], 0,0,0);
        g[nt] = __builtin_amdgcn_mfma_f32_16x16x32_bf16(a_, bl, g[nt], 0,0,0);
      }
    }
    #pragma unroll
    for (int nt=0; nt<4; nt++)
      #pragma unroll
      for (int r=0;r<4;r++){
        float gvv = g[nt][r];
        nrm += gvv*gvv;
        G1[(size_t)inst*65536 + (size_t)(16*w + quad*4 + r)*512 + j0 + nt*16 + n_l] = -gvv;
      }
  }
  #pragma unroll
  for (int o=32;o>0;o>>=1) nrm += __shfl_down(nrm, o, 64);
  __syncthreads();
  float* red8 = (float*)wb;
  if (lane==0) red8[w]=nrm;
  __syncthreads();
  if (tid==0){
    float s=0;
    #pragma unroll
    for (int i=0;i<8;i++) s+=red8[i];
    norm2[inst] = s;
  }
}

// ---------------- NS fused A+B (512 thr): A = t@t^T (regs); acc seeded (CB/CC)A; B = CC*(A@A) ----------------
__global__ __launch_bounds__(512) void k_nsAB(const float* __restrict__ G1, const float* __restrict__ G2T,
                                              const float* __restrict__ norm2,
                                              unsigned short* __restrict__ ABh, unsigned short* __restrict__ ABl,
                                              int first){
  int m = blockIdx.x;
  const float* t = (m<256)? (G1 + (size_t)m*65536) : (G2T + (size_t)(m-256)*65536);
  float scl = first ? 1.0f/fmaxf(sqrtf(norm2[m]), 1e-7f) : 1.0f;
  __shared__ unsigned short th[16384];
  __shared__ unsigned short tl[16384];
  int tid = threadIdx.x;
  int w = tid>>6, lane = tid&63;     // w: 0..7, rows 16w
  int n = lane&15, quad = lane>>4;
  v4f acc[8];
  #pragma unroll
  for (int j=0;j<8;j++){ v4f z = {0.f,0.f,0.f,0.f}; acc[j]=z; }
  for (int c=0;c<4;c++){
    int k0 = c*128;
    for (int it=0; it<8; it++){
      int idx = it*2048 + tid*4;
      int r = idx>>7, k = idx&127;
      float4 v = *(const float4*)(t + (size_t)r*512 + k0 + k);
      v.x*=scl; v.y*=scl; v.z*=scl; v.w*=scl;
      union { unsigned long long q; unsigned short s[4]; } uh, ulw;
      hilo(v.x,uh.s[0],ulw.s[0]); hilo(v.y,uh.s[1],ulw.s[1]);
      hilo(v.z,uh.s[2],ulw.s[2]); hilo(v.w,uh.s[3],ulw.s[3]);
      *(unsigned long long*)&th[swz(r,k)] = uh.q;
      *(unsigned long long*)&tl[swz(r,k)] = ulw.q;
    }
    __syncthreads();
    for (int kk=0; kk<128; kk+=32){
      int kf = kk + quad*8;
      v8s ah = *(const v8s*)&th[swz(16*w + n, kf)];
      v8s al = *(const v8s*)&tl[swz(16*w + n, kf)];
      #pragma unroll
      for (int j=0;j<8;j++){
        v8s bh = *(const v8s*)&th[swz(j*16 + n, kf)];
        v8s bl = *(const v8s*)&tl[swz(j*16 + n, kf)];
        acc[j] = __builtin_amdgcn_mfma_f32_16x16x32_bf16(ah, bh, acc[j], 0,0,0);
        acc[j] = __builtin_amdgcn_mfma_f32_16x16x32_bf16(ah, bl, acc[j], 0,0,0);
        acc[j] = __builtin_amdgcn_mfma_f32_16x16x32_bf16(al, bh, acc[j], 0,0,0);
      }
    }
    __syncthreads();
  }
  const float CB=-4.775f, CC=2.0315f, CBoverCC = CB/CC;
  #pragma unroll
  for (int j=0;j<8;j++)
    #pragma unroll
    for (int r=0;r<4;r++){
      int row = 16*w + quad*4 + r;
      int col = j*16 + n;
      float av = acc[j][r];
      unsigned short hs, ls;
      hilo(av, hs, ls);
      th[swz(row,col)] = hs;
      tl[swz(row,col)] = ls;
      acc[j][r] = CBoverCC*av;
    }
  __syncthreads();
  for (int kk=0; kk<128; kk+=32){
    int kf = kk + quad*8;
    v8s ah = *(const v8s*)&th[swz(16*w + n, kf)];
    v8s al = *(const v8s*)&tl[swz(16*w + n, kf)];
    #pragma unroll
    for (int j=0;j<8;j++){
      v8s bh = *(const v8s*)&th[swz(j*16 + n, kf)];
      v8s bl = *(const v8s*)&tl[swz(j*16 + n, kf)];
      acc[j] = __builtin_amdgcn_mfma_f32_16x16x32_bf16(ah, bh, acc[j], 0,0,0);
      acc[j] = __builtin_amdgcn_mfma_f32_16x16x32_bf16(ah, bl, acc[j], 0,0,0);
      acc[j] = __builtin_amdgcn_mfma_f32_16x16x32_bf16(al, bh, acc[j], 0,0,0);
    }
  }
  __syncthreads();
  #pragma unroll
  for (int j=0;j<8;j++)
    #pragma unroll
    for (int r=0;r<4;r++){
      int row = 16*w + quad*4 + r;
      int col = j*16 + n;
      float v = CC*acc[j][r];
      unsigned short hs, ls;
      hilo(v, hs, ls);
      th[row*128+col] = hs;
      tl[row*128+col] = ls;
    }
  __syncthreads();
  for (int it=0; it<4; it++){
    int idx = it*4096 + tid*8;
    *(v8s*)&ABh[(size_t)m*16384 + idx] = *(const v8s*)&th[idx];
    *(v8s*)&ABl[(size_t)m*16384 + idx] = *(const v8s*)&tl[idx];
  }
}

// ---------------- NS step 2 (512 thr, 64KB, K-chunk 64, Zs epilogue; XCD swizzle) ----------------
__global__ __launch_bounds__(512) void k_nsZ(float* __restrict__ G1, float* __restrict__ G2T,
                                             const unsigned short* __restrict__ ABh, const unsigned short* __restrict__ ABl,
                                             const float* __restrict__ norm2, int first){
  int blk = blockIdx.x;
  int m = (blk>>5)*8 + (blk&7);
  int s = (blk>>3)&3, c0 = s*128;
  float* t = (m<256)? (G1 + (size_t)m*65536) : (G2T + (size_t)(m-256)*65536);
  float scl = first ? 1.0f/fmaxf(sqrtf(norm2[m]), 1e-7f) : 1.0f;
  __shared__ __align__(16) unsigned char smem[65536];
  unsigned short* Bh = (unsigned short*)smem;
  unsigned short* Bl = Bh + 8192;
  unsigned short* uh = Bh + 16384;
  unsigned short* ul = Bh + 24576;
  float* Zs = (float*)smem;
  int tid = threadIdx.x;
  int w = tid>>6, lane = tid&63;      // w: 0..7, rows 16w
  int n = lane&15, quad = lane>>4;
  v4f acc[8];
  #pragma unroll
  for (int j=0;j<8;j++){ v4f z = {0.f,0.f,0.f,0.f}; acc[j]=z; }
  for (int c=0;c<2;c++){
    int k0 = c*64;
    for (int it=0; it<2; it++){
      int idx = it*4096 + tid*8;
      int r = idx>>6, k = idx&63;
      *(v8s*)&Bh[swz64(r,k)] = *(const v8s*)&ABh[(size_t)m*16384 + (size_t)r*128 + k0 + k];
      *(v8s*)&Bl[swz64(r,k)] = *(const v8s*)&ABl[(size_t)m*16384 + (size_t)r*128 + k0 + k];
    }
    for (int it=0; it<4; it++){
      int idx = it*2048 + tid*4;
      int kr = idx>>7, j = idx&127;
      float4 v = *(const float4*)(t + (size_t)(k0+kr)*512 + c0 + j);
      float vv[4] = {v.x*scl, v.y*scl, v.z*scl, v.w*scl};
      #pragma unroll
      for (int e=0;e<4;e++){
        unsigned short hs = f2bs(vv[e]);
        uh[swz64(j+e, kr)] = hs;
        ul[swz64(j+e, kr)] = f2bs(vv[e] - bs2f(hs));
      }
    }
    __syncthreads();
    #pragma unroll
    for (int kk=0; kk<64; kk+=32){
      int kf = kk + quad*8;
      v8s ah = *(const v8s*)&Bh[swz64(16*w + n, kf)];
      v8s al = *(const v8s*)&Bl[swz64(16*w + n, kf)];
      #pragma unroll
      for (int j=0;j<8;j++){
        v8s bh = *(const v8s*)&uh[swz64(j*16 + n, kf)];
        v8s bl = *(const v8s*)&ul[swz64(j*16 + n, kf)];
        acc[j] = __builtin_amdgcn_mfma_f32_16x16x32_bf16(ah, bh, acc[j], 0,0,0);
        acc[j] = __builtin_amdgcn_mfma_f32_16x16x32_bf16(ah, bl, acc[j], 0,0,0);
        acc[j] = __builtin_amdgcn_mfma_f32_16x16x32_bf16(al, bh, acc[j], 0,0,0);
      }
    }
    __syncthreads();
  }
  #pragma unroll
  for (int j=0;j<8;j++)
    #pragma unroll
    for (int r=0;r<4;r++)
      Zs[(16*w + quad*4 + r)*128 + j*16 + n] = acc[j][r];
  __syncthreads();
  const float CA = 3.4445f;
  for (int it=0; it<8; it++){
    int idx = it*2048 + tid*4;
    int i = idx>>7, j = idx&127;
    float* dst = t + (size_t)i*512 + c0 + j;
    float4 told = *(const float4*)dst;
    float4 o;
    o.x = CA*(told.x*scl) + Zs[i*128+j+0];
    o.y = CA*(told.y*scl) + Zs[i*128+j+1];
    o.z = CA*(told.z*scl) + Zs[i*128+j+2];
    o.w = CA*(told.w*scl) + Zs[i*128+j+3];
    *(float4*)dst = o;
  }
}

// ---------------- momentum + decay scans (float4/thread, prefetch), per (b,h) strand ----------------
__global__ __launch_bounds__(256) void k_scan_mat(float* __restrict__ G, const float* __restrict__ mw,
    const float* __restrict__ MOMb, const float* __restrict__ DECb, int transposed){
  int bh = blockIdx.x>>6;
  int eblk = blockIdx.x&63;
  int e = (eblk*256 + threadIdx.x)*4;
  int h = bh&3;
  float4 u;
  if (transposed){
    int d = e>>9; int j = e&511;
    u.x = mw[(size_t)h*65536 + (size_t)(j+0)*128 + d];
    u.y = mw[(size_t)h*65536 + (size_t)(j+1)*128 + d];
    u.z = mw[(size_t)h*65536 + (size_t)(j+2)*128 + d];
    u.w = mw[(size_t)h*65536 + (size_t)(j+3)*128 + d];
  } else {
    u = *(const float4*)(mw + (size_t)h*65536 + e);
  }
  float4 mval = {0,0,0,0};
  size_t base = (size_t)(bh*32)*65536 + e;
  float4 s = *(const float4*)(G + base);
  for (int ci=0; ci<32; ci++){
    size_t off = base + (size_t)ci*65536;
    float4 s_next;
    if (ci<31) s_next = *(const float4*)(G + off + 65536);
    float mo = MOMb[bh*32+ci], de = DECb[bh*32+ci];
    float om = 1.0f-de;
    mval.x = mo*mval.x + s.x; mval.y = mo*mval.y + s.y;
    mval.z = mo*mval.z + s.z; mval.w = mo*mval.w + s.w;
    u.x = om*u.x + mval.x; u.y = om*u.y + mval.y;
    u.z = om*u.z + mval.z; u.w = om*u.w + mval.w;
    *(float4*)(G + off) = u;
    s = s_next;
  }
}

__global__ __launch_bounds__(128) void k_scan_gamma(float* __restrict__ GG, const float* __restrict__ mg,
    const float* __restrict__ MOMb, const float* __restrict__ DECb){
  int bh=blockIdx.x; int e=threadIdx.x; int h=bh&3;
  float u = mg[h*128+e]; float mval=0;
  for (int ci=0;ci<32;ci++){
    size_t off = ((size_t)(bh*32+ci))*128 + e;
    float s = GG[off];
    float mo = MOMb[bh*32+ci], de = DECb[bh*32+ci];
    mval = mo*mval + s;
    u = (1.0f-de)*u + mval;
    GG[off]=u;
  }
}

// ---------------- retrieval (MFMA, 512 thr, 4x2 wave grid) ----------------
__global__ __launch_bounds__(512) void k_retr(const float* __restrict__ Qb, const float* __restrict__ G1,
   const float* __restrict__ G2T, const float* __restrict__ GG, const float* __restrict__ mw1,
   const float* __restrict__ mw2, const float* __restrict__ mgamma,
   const float* __restrict__ GATEb, float* __restrict__ OUTT){
  int inst = blockIdx.x;
  int ci = inst & 31, h = (inst>>5)&3, b = inst>>7;
  size_t tok0 = (size_t)b*NN_ + (size_t)ci*64;
  int tid = threadIdx.x, w = tid>>6, lane = tid&63, n_l = lane&15, quad = lane>>4;
  int wm = w&3, wn = w>>2;
  __shared__ unsigned short xh[8192];
  __shared__ unsigned short wbh[8192], wbl[8192];
  __shared__ unsigned short ash[4096], asl[4096];
  const int first = (ci==0);
  const float* w1 = first ? (mw1 + (size_t)h*65536) : (G1 + (size_t)(inst-1)*65536);
  const float* w2j = mw2 + (size_t)h*65536;
  const float* w2d = G2T + (size_t)(inst-1)*65536;
  for (int it=0; it<4; it++){
    int idx = it*2048 + tid*4;
    int r = idx>>7, d = idx&127;
    float4 v = *(const float4*)(Qb + (tok0+r)*512 + h*128 + d);
    int p = swz(r,d);
    *(unsigned*)&xh[p]   = (unsigned)f2bs(v.x)|((unsigned)f2bs(v.y)<<16);
    *(unsigned*)&xh[p+2] = (unsigned)f2bs(v.z)|((unsigned)f2bs(v.w)<<16);
  }
  v4f acc2[4];
  #pragma unroll
  for (int j=0;j<4;j++){ v4f z={0.f,0.f,0.f,0.f}; acc2[j]=z; }
  for (int jt=0; jt<8; jt++){
    int j0 = jt*64;
    __syncthreads();
    for (int it=0; it<4; it++){
      int idx = it*2048 + tid*4;
      int d = idx>>6, jj = idx&63;
      float4 v = *(const float4*)(w1 + (size_t)d*512 + j0 + jj);
      unsigned short hh,ll;
      hilo(v.x,hh,ll); wbh[swz(jj+0,d)]=hh; wbl[swz(jj+0,d)]=ll;
      hilo(v.y,hh,ll); wbh[swz(jj+1,d)]=hh; wbl[swz(jj+1,d)]=ll;
      hilo(v.z,hh,ll); wbh[swz(jj+2,d)]=hh; wbl[swz(jj+2,d)]=ll;
      hilo(v.w,hh,ll); wbh[swz(jj+3,d)]=hh; wbl[swz(jj+3,d)]=ll;
    }
    __syncthreads();
    v4f acc1[2];
    #pragma unroll
    for (int nt=0; nt<2; nt++){ v4f z={0.f,0.f,0.f,0.f}; acc1[nt]=z; }
    #pragma unroll
    for (int ks=0; ks<4; ks++){
      int kf = ks*32 + quad*8;
      v8s av = *(const v8s*)&xh[swz(16*wm + n_l, kf)];
      #pragma unroll
      for (int nt=0; nt<2; nt++){
        int jj = wn*32 + nt*16 + n_l;
        v8s bh = *(const v8s*)&wbh[swz(jj, kf)];
        v8s bl = *(const v8s*)&wbl[swz(jj, kf)];
        acc1[nt] = __builtin_amdgcn_mfma_f32_16x16x32_bf16(av, bh, acc1[nt], 0,0,0);
        acc1[nt] = __builtin_amdgcn_mfma_f32_16x16x32_bf16(av, bl, acc1[nt], 0,0,0);
      }
    }
    #pragma unroll
    for (int nt=0; nt<2; nt++)
      #pragma unroll
      for (int r=0;r<4;r++){
        int t = 16*wm + quad*4 + r;
        int jj = wn*32 + nt*16 + n_l;
        float g = geluf(acc1[nt][r]);
        unsigned short gh = f2bs(g);
        ash[swz64(t, jj)] = gh;
        asl[swz64(t, jj)] = f2bs(g - bs2f(gh));
      }
    __syncthreads();
    if (first){
      for (int it=0; it<4; it++){
        int idx = it*2048 + tid*4;
        int jj = idx>>7, d = idx&127;
        float4 v = *(const float4*)(w2j + (size_t)(j0+jj)*128 + d);
        unsigned short hh,ll;
        hilo(v.x,hh,ll); wbh[swz64(d+0,jj)]=hh; wbl[swz64(d+0,jj)]=ll;
        hilo(v.y,hh,ll); wbh[swz64(d+1,jj)]=hh; wbl[swz64(d+1,jj)]=ll;
        hilo(v.z,hh,ll); wbh[swz64(d+2,jj)]=hh; wbl[swz64(d+2,jj)]=ll;
        hilo(v.w,hh,ll); wbh[swz64(d+3,jj)]=hh; wbl[swz64(d+3,jj)]=ll;
      }
    } else {
      for (int it=0; it<4; it++){
        int idx = it*2048 + tid*4;
        int d = idx>>6, jj = idx&63;
        float4 v = *(const float4*)(w2d + (size_t)d*512 + j0 + jj);
        unsigned short h0,h1,h2,h3,l0,l1,l2,l3;
        hilo(v.x,h0,l0); hilo(v.y,h1,l1); hilo(v.z,h2,l2); hilo(v.w,h3,l3);
        int p = swz64(d,jj);
        *(unsigned*)&wbh[p]   = (unsigned)h0|((unsigned)h1<<16);
        *(unsigned*)&wbh[p+2] = (unsigned)h2|((unsigned)h3<<16);
        *(unsigned*)&wbl[p]   = (unsigned)l0|((unsigned)l1<<16);
        *(unsigned*)&wbl[p+2] = (unsigned)l2|((unsigned)l3<<16);
      }
    }
    __syncthreads();
    #pragma unroll
    for (int ks=0; ks<2; ks++){
      int kf = ks*32 + quad*8;
      v8s ah = *(const v8s*)&ash[swz64(16*wm + n_l, kf)];
      v8s al = *(const v8s*)&asl[swz64(16*wm + n_l, kf)];
      #pragma unroll
      for (int nt=0; nt<4; nt++){
        int dc = wn*64 + nt*16 + n_l;
        v8s bh = *(const v8s*)&wbh[swz64(dc, kf)];
        v8s bl = *(const v8s*)&wbl[swz64(dc, kf)];
        acc2[nt] = __builtin_amdgcn_mfma_f32_16x16x32_bf16(ah, bh, acc2[nt], 0,0,0);
        acc2[nt] = __builtin_amdgcn_mfma_f32_16x16x32_bf16(ah, bl, acc2[nt], 0,0,0);
        acc2[nt] = __builtin_amdgcn_mfma_f32_16x16x32_bf16(al, bh, acc2[nt], 0,0,0);
      }
    }
  }
  float* red = (float*)wbh;   // [0..127]: ssh[2][64]
  __syncthreads();
  float ss[4] = {0,0,0,0};
  #pragma unroll
  for (int nt=0; nt<4; nt++)
    #pragma unroll
    for (int r=0;r<4;r++) ss[r] += acc2[nt][r]*acc2[nt][r];
  #pragma unroll
  for (int m=1;m<16;m<<=1)
    #pragma unroll
    for (int r=0;r<4;r++) ss[r] += __shfl_xor(ss[r], m, 64);
  if (n_l==0){
    #pragma unroll
    for (int r=0;r<4;r++) red[wn*64 + 16*wm + quad*4 + r] = ss[r];
  }
  __syncthreads();
  float rr[4];
  #pragma unroll
  for (int r=0;r<4;r++){
    int row = 16*wm + quad*4 + r;
    float tot = red[row] + red[64 + row];
    rr[r] = rsqrtf(tot*(1.0f/128.0f) + 1e-6f);
  }
  float gv[4];
  #pragma unroll
  for (int nt=0; nt<4; nt++){
    int d = wn*64 + nt*16 + n_l;
    gv[nt] = first ? mgamma[h*128+d] : GG[(size_t)(inst-1)*128+d];
  }
  float gate[4];
  #pragma unroll
  for (int r=0;r<4;r++) gate[r] = GATEb[(tok0 + 16*wm + quad*4 + r)*4 + h];
  #pragma unroll
  for (int nt=0; nt<4; nt++)
    #pragma unroll
    for (int r=0;r<4;r++){
      int t = 16*wm + quad*4 + r;
      int d = wn*64 + nt*16 + n_l;
      float qv = Qb[(tok0+t)*512 + h*128 + d];
      OUTT[(tok0+t)*512 + h*128 + d] = (acc2[nt][r]*rr[r]*gv[nt] + qv)*gate[r];
    }
}

extern "C" void kernel_launch(void* const* d_in, const int* in_sizes, int n_in,
                              void* d_out, int out_size, void* d_ws, size_t ws_size,
                              hipStream_t stream) {
  (void)in_sizes; (void)n_in; (void)out_size; (void)ws_size;
  const float* seq   = (const float*)d_in[0];
  const float* sg    = (const float*)d_in[1];
  const float* rg    = (const float*)d_in[2];
  const float* Wq    = (const float*)d_in[3];
  const float* Wk    = (const float*)d_in[4];
  const float* Wv    = (const float*)d_in[5];
  const float* Wlr   = (const float*)d_in[6];
  const float* blr   = (const float*)d_in[7];
  const float* Wm    = (const float*)d_in[8];
  const float* bm    = (const float*)d_in[9];
  const float* Wd    = (const float*)d_in[10];
  const float* bd    = (const float*)d_in[11];
  const float* Wgate = (const float*)d_in[12];
  const float* Wc    = (const float*)d_in[13];
  const float* mw1   = (const float*)d_in[14];
  const float* mw2   = (const float*)d_in[15];
  const float* mgam  = (const float*)d_in[16];

  float* W = (float*)d_ws;
  float* S    = W + 0;
  float* SR   = W + 2097152;
  float* Kb   = W + 4194304;
  float* Vb   = W + 6291456;
  float* H1T  = W + 8388608;
  float* DH2  = W + 16777216;
  float* Qb   = W + 18874368;
  float* LRb  = W + 20971520;
  float* GATEb= W + 20987904;
  float* MOMb = W + 21004288;
  float* DECb = W + 21004544;
  float* GGb  = W + 21004800;
  float* G1   = W + 21037568;
  float* G2T  = W + 37814784;
  float* NRM2 = W + 54592000;   // 512 floats
  unsigned short* ABh = (unsigned short*)(W + 0);        // overlay S+SR (dead by NS time)
  unsigned short* ABl = (unsigned short*)(W + 4194304);  // overlay Kb+Vb (dead after k_dw1)
  float* OUTT = W + 8388608;  // overlay H1T slot (free by retrieval time)

  k_rmsnorm<<<4096,256,0,stream>>>(seq, sg, rg, S, SR);
  dim3 gg(64,4);
  k_gemm_mfma<<<gg,256,0,stream>>>(S,  Wk, Kb);
  k_gemm_mfma<<<gg,256,0,stream>>>(S,  Wv, Vb);
  k_gemm_mfma<<<gg,256,0,stream>>>(SR, Wq, Qb);
  k_small<<<64,256,0,stream>>>(S, SR, Wlr, blr, Wm, bm, Wd, bd, Wgate, LRb, GATEb, MOMb, DECb);
  k_fwd<<<256,512,0,stream>>>(Kb, Vb, LRb, mw1, mw2, mgam, H1T, DH2, GGb);
  k_dw2<<<256,512,0,stream>>>(DH2, H1T, G2T, NRM2);
  k_dw1<<<256,512,0,stream>>>(Kb, DH2, H1T, mw2, G1, NRM2);
  for (int it=0; it<5; it++){
    k_nsAB<<<512,512,0,stream>>>(G1, G2T, NRM2, ABh, ABl, it==0);
    k_nsZ<<<2048,512,0,stream>>>(G1, G2T, ABh, ABl, NRM2, it==0);
  }
  k_scan_mat<<<512,256,0,stream>>>(G1,  mw1, MOMb, DECb, 0);
  k_scan_mat<<<512,256,0,stream>>>(G2T, mw2, MOMb, DECb, 1);
  k_scan_gamma<<<8,128,0,stream>>>(GGb, mgam, MOMb, DECb);
  k_retr<<<256,512,0,stream>>>(Qb, G1, G2T, GGb, mw1, mw2, mgam, GATEb, OUTT);
  k_gemm_mfma<<<gg,256,0,stream>>>(OUTT, Wc, (float*)d_out);
}

// Round 13
// 1047.704 us; speedup vs baseline: 1.1434x; 1.0162x over previous
//
#include <hip/hip_runtime.h>
#include <hip/hip_bf16.h>
#include <math.h>

#define NN_ 2048

typedef short v8s __attribute__((ext_vector_type(8)));
typedef float v4f __attribute__((ext_vector_type(4)));

__device__ __forceinline__ float geluf(float x){ return 0.5f*x*(1.0f+erff(x*0.70710678118654752440f)); }
__device__ __forceinline__ float gelupf(float x){
  float cdf = 0.5f*(1.0f+erff(x*0.70710678118654752440f));
  float pdf = 0.39894228040143267794f*expf(-0.5f*x*x);
  return cdf + x*pdf;
}
__device__ __forceinline__ float sigm(float x){ return 1.0f/(1.0f+expf(-x)); }

__device__ __forceinline__ unsigned short f2bs(float f){
  __hip_bfloat16 h = __float2bfloat16(f);
  return __builtin_bit_cast(unsigned short, h);
}
__device__ __forceinline__ float bs2f(unsigned short u){
  unsigned v = ((unsigned)u)<<16;
  return __builtin_bit_cast(float, v);
}
__device__ __forceinline__ void hilo(float v, unsigned short &h, unsigned short &l){
  h = f2bs(v); l = f2bs(v - bs2f(h));
}
// XOR swizzle folding (r>>2): transpose-staging writes spread across bank groups
__device__ __forceinline__ int swz(int r, int k){
  return r*128 + ((((k>>3) ^ (r&15) ^ ((r>>2)&15)) & 15)<<3) + (k&7);
}
__device__ __forceinline__ int swz64(int r, int k){
  return r*64 + ((((k>>3) ^ (r&7) ^ ((r>>2)&7)) & 7)<<3) + (k&7);
}

// ---------------- rmsnorm of seq with store/retrieve gains ----------------
__global__ __launch_bounds__(256) void k_rmsnorm(const float* __restrict__ seq, const float* __restrict__ gs,
                          const float* __restrict__ gr, float* __restrict__ S, float* __restrict__ SR){
  int tok = blockIdx.x;
  const float* row = seq + (size_t)tok*512;
  int tid = threadIdx.x;
  float x0 = row[tid];
  float x1 = row[tid+256];
  float ss = x0*x0 + x1*x1;
  #pragma unroll
  for (int o=32;o>0;o>>=1) ss += __shfl_down(ss, o, 64);
  __shared__ float wsum[4];
  int wid = tid>>6, lid = tid&63;
  if (lid==0) wsum[wid]=ss;
  __syncthreads();
  float tot = wsum[0]+wsum[1]+wsum[2]+wsum[3];
  float r = rsqrtf(tot*(1.0f/512.0f) + 1e-6f);
  size_t o0 = (size_t)tok*512 + tid;
  S[o0]      = x0*r*gs[tid];
  S[o0+256]  = x1*r*gs[tid+256];
  SR[o0]     = x0*r*gr[tid];
  SR[o0+256] = x1*r*gr[tid+256];
}

// ---------------- MFMA GEMM: O[4096x512] = X @ Wt, hi/lo, 64x128 tiles ----------------
__global__ __launch_bounds__(256) void k_gemm_mfma(const float* __restrict__ X, const float* __restrict__ Wt,
                                                   float* __restrict__ O){
  int m0 = blockIdx.x*64, n0 = blockIdx.y*128;
  __shared__ unsigned short Xh[4096], Xl[4096], Wh[8192], Wl[8192];
  int tid = threadIdx.x, w = tid>>6, lane = tid&63, n_l = lane&15, quad = lane>>4;
  v4f acc[8];
  #pragma unroll
  for (int j=0;j<8;j++){ v4f z={0.f,0.f,0.f,0.f}; acc[j]=z; }
  for (int kc=0; kc<8; kc++){
    int k0 = kc*64;
    __syncthreads();
    for (int it=0; it<4; it++){
      int idx = it*1024 + tid*4;
      int r = idx>>6, k = idx&63;
      float4 v = *(const float4*)(X + (size_t)(m0+r)*512 + k0 + k);
      union { unsigned long long q; unsigned short s[4]; } uh, ul;
      hilo(v.x,uh.s[0],ul.s[0]); hilo(v.y,uh.s[1],ul.s[1]);
      hilo(v.z,uh.s[2],ul.s[2]); hilo(v.w,uh.s[3],ul.s[3]);
      int p = swz64(r,k);
      *(unsigned long long*)&Xh[p] = uh.q;
      *(unsigned long long*)&Xl[p] = ul.q;
    }
    for (int it=0; it<8; it++){
      int idx = it*1024 + tid*4;
      int k = idx>>7, n = idx&127;
      float4 v = *(const float4*)(Wt + (size_t)(k0+k)*512 + n0 + n);
      unsigned short hh,ll;
      hilo(v.x,hh,ll); Wh[swz64(n+0,k)]=hh; Wl[swz64(n+0,k)]=ll;
      hilo(v.y,hh,ll); Wh[swz64(n+1,k)]=hh; Wl[swz64(n+1,k)]=ll;
      hilo(v.z,hh,ll); Wh[swz64(n+2,k)]=hh; Wl[swz64(n+2,k)]=ll;
      hilo(v.w,hh,ll); Wh[swz64(n+3,k)]=hh; Wl[swz64(n+3,k)]=ll;
    }
    __syncthreads();
    #pragma unroll
    for (int ks=0; ks<2; ks++){
      int kf = ks*32 + quad*8;
      v8s ah = *(const v8s*)&Xh[swz64(16*w + n_l, kf)];
      v8s al = *(const v8s*)&Xl[swz64(16*w + n_l, kf)];
      #pragma unroll
      for (int nt=0; nt<8; nt++){
        v8s bh = *(const v8s*)&Wh[swz64(nt*16+n_l, kf)];
        v8s bl = *(const v8s*)&Wl[swz64(nt*16+n_l, kf)];
        acc[nt] = __builtin_amdgcn_mfma_f32_16x16x32_bf16(ah, bh, acc[nt], 0,0,0);
        acc[nt] = __builtin_amdgcn_mfma_f32_16x16x32_bf16(ah, bl, acc[nt], 0,0,0);
        acc[nt] = __builtin_amdgcn_mfma_f32_16x16x32_bf16(al, bh, acc[nt], 0,0,0);
      }
    }
  }
  #pragma unroll
  for (int nt=0; nt<8; nt++)
    #pragma unroll
    for (int r=0;r<4;r++)
      O[(size_t)(m0 + 16*w + quad*4 + r)*512 + n0 + nt*16 + n_l] = acc[nt][r];
}

// ---------------- lr/gate per token, pooled->mom/dec per chunk ----------------
__global__ __launch_bounds__(256) void k_small(const float* __restrict__ S, const float* __restrict__ SR,
    const float* __restrict__ Wlr, const float* __restrict__ blr, const float* __restrict__ Wm,
    const float* __restrict__ bm, const float* __restrict__ Wd, const float* __restrict__ bd,
    const float* __restrict__ Wgate,
    float* __restrict__ LRb, float* __restrict__ GATEb, float* __restrict__ MOMb, float* __restrict__ DECb){
  int bc = blockIdx.x;            // b*32 + ci
  int b = bc>>5, ci = bc&31;
  int tid = threadIdx.x;
  int t = tid>>2, h = tid&3;
  size_t tokbase = (size_t)b*NN_ + (size_t)ci*64;
  __shared__ float pool[512];
  for (int c=tid; c<512; c+=256){
    float s=0;
    for (int t2=0;t2<64;t2++) s += S[(tokbase+t2)*512 + c];
    pool[c] = s*(1.0f/64.0f);
  }
  size_t tok = tokbase + t;
  const float* srow = S + tok*512;
  const float* srrow = SR + tok*512;
  float accl=0, accg=0;
  for (int d=0; d<512; d++){
    accl += srow[d]*Wlr[d*4+h];
    accg += srrow[d]*Wgate[d*4+h];
  }
  accl += blr[h];
  LRb[tok*4+h] = sigm(accl);
  GATEb[tok*4+h] = sigm(accg);
  __syncthreads();
  if (tid<8){
    int hh = tid&3, which = tid>>2;
    float a=0;
    const float* Wx = which? Wd : Wm;
    for (int d=0; d<512; d++) a += pool[d]*Wx[d*4+hh];
    a += which? bd[hh] : bm[hh];
    float v = sigm(a);
    size_t o = ((size_t)b*4+hh)*32 + ci;
    if (which) DECb[o]=v; else MOMb[o]=v;
  }
}

// ---------------- fused memory-MLP forward + rmsnorm backward (MFMA, 512 thr, 4x2 wave grid) ----------------
__global__ __launch_bounds__(512) void k_fwd(const float* __restrict__ Kb, const float* __restrict__ Vb,
    const float* __restrict__ LRb, const float* __restrict__ mw1, const float* __restrict__ mw2,
    const float* __restrict__ mgamma, float* __restrict__ H1T, float* __restrict__ DH2,
    float* __restrict__ GG){
  int inst = blockIdx.x;
  int ci = inst & 31, h = (inst>>5)&3, b = inst>>7;
  size_t tok0 = (size_t)b*NN_ + (size_t)ci*64;
  int tid = threadIdx.x, w = tid>>6, lane = tid&63, n_l = lane&15, quad = lane>>4;
  int wm = w&3, wn = w>>2;          // wm: token-quarter (16 rows), wn: N-half
  __shared__ unsigned short xh[8192];              // [64 t][128 d] swz, hi only
  __shared__ unsigned short wbh[8192], wbl[8192];  // weight tile
  __shared__ unsigned short ash[4096], asl[4096];  // gelu(h1) tile [64 t][64 j] swz64
  const float* w1 = mw1 + (size_t)h*65536;  // [128 d][512 j]
  const float* w2 = mw2 + (size_t)h*65536;  // [512 j][128 d]
  for (int it=0; it<4; it++){
    int idx = it*2048 + tid*4;
    int r = idx>>7, d = idx&127;
    float4 v = *(const float4*)(Kb + (tok0+r)*512 + h*128 + d);
    int p = swz(r,d);
    *(unsigned*)&xh[p]   = (unsigned)f2bs(v.x)|((unsigned)f2bs(v.y)<<16);
    *(unsigned*)&xh[p+2] = (unsigned)f2bs(v.z)|((unsigned)f2bs(v.w)<<16);
  }
  v4f acc2[4];
  #pragma unroll
  for (int j=0;j<4;j++){ v4f z={0.f,0.f,0.f,0.f}; acc2[j]=z; }
  for (int jt=0; jt<8; jt++){
    int j0 = jt*64;
    __syncthreads();
    for (int it=0; it<4; it++){
      int idx = it*2048 + tid*4;
      int d = idx>>6, jj = idx&63;
      float4 v = *(const float4*)(w1 + (size_t)d*512 + j0 + jj);
      unsigned short hh,ll;
      hilo(v.x,hh,ll); wbh[swz(jj+0,d)]=hh; wbl[swz(jj+0,d)]=ll;
      hilo(v.y,hh,ll); wbh[swz(jj+1,d)]=hh; wbl[swz(jj+1,d)]=ll;
      hilo(v.z,hh,ll); wbh[swz(jj+2,d)]=hh; wbl[swz(jj+2,d)]=ll;
      hilo(v.w,hh,ll); wbh[swz(jj+3,d)]=hh; wbl[swz(jj+3,d)]=ll;
    }
    __syncthreads();
    v4f acc1[2];
    #pragma unroll
    for (int nt=0; nt<2; nt++){ v4f z={0.f,0.f,0.f,0.f}; acc1[nt]=z; }
    #pragma unroll
    for (int ks=0; ks<4; ks++){
      int kf = ks*32 + quad*8;
      v8s av = *(const v8s*)&xh[swz(16*wm + n_l, kf)];
      #pragma unroll
      for (int nt=0; nt<2; nt++){
        int jj = wn*32 + nt*16 + n_l;
        v8s bh = *(const v8s*)&wbh[swz(jj, kf)];
        v8s bl = *(const v8s*)&wbl[swz(jj, kf)];
        acc1[nt] = __builtin_amdgcn_mfma_f32_16x16x32_bf16(av, bh, acc1[nt], 0,0,0);
        acc1[nt] = __builtin_amdgcn_mfma_f32_16x16x32_bf16(av, bl, acc1[nt], 0,0,0);
      }
    }
    #pragma unroll
    for (int nt=0; nt<2; nt++){
      int jj = wn*32 + nt*16 + n_l;
      float4 hv4;
      hv4.x = acc1[nt][0]; hv4.y = acc1[nt][1]; hv4.z = acc1[nt][2]; hv4.w = acc1[nt][3];
      *(float4*)(H1T + (size_t)inst*32768 + (size_t)(j0+jj)*64 + 16*wm + quad*4) = hv4;
      #pragma unroll
      for (int r=0;r<4;r++){
        int t = 16*wm + quad*4 + r;
        float g = geluf(acc1[nt][r]);
        unsigned short gh = f2bs(g);
        ash[swz64(t, jj)] = gh;
        asl[swz64(t, jj)] = f2bs(g - bs2f(gh));
      }
    }
    __syncthreads();
    for (int it=0; it<4; it++){
      int idx = it*2048 + tid*4;
      int jj = idx>>7, d = idx&127;
      float4 v = *(const float4*)(w2 + (size_t)(j0+jj)*128 + d);
      unsigned short hh,ll;
      hilo(v.x,hh,ll); wbh[swz64(d+0,jj)]=hh; wbl[swz64(d+0,jj)]=ll;
      hilo(v.y,hh,ll); wbh[swz64(d+1,jj)]=hh; wbl[swz64(d+1,jj)]=ll;
      hilo(v.z,hh,ll); wbh[swz64(d+2,jj)]=hh; wbl[swz64(d+2,jj)]=ll;
      hilo(v.w,hh,ll); wbh[swz64(d+3,jj)]=hh; wbl[swz64(d+3,jj)]=ll;
    }
    __syncthreads();
    #pragma unroll
    for (int ks=0; ks<2; ks++){
      int kf = ks*32 + quad*8;
      v8s ah = *(const v8s*)&ash[swz64(16*wm + n_l, kf)];
      v8s al = *(const v8s*)&asl[swz64(16*wm + n_l, kf)];
      #pragma unroll
      for (int nt=0; nt<4; nt++){
        int dc = wn*64 + nt*16 + n_l;
        v8s bh = *(const v8s*)&wbh[swz64(dc, kf)];
        v8s bl = *(const v8s*)&wbl[swz64(dc, kf)];
        acc2[nt] = __builtin_amdgcn_mfma_f32_16x16x32_bf16(ah, bh, acc2[nt], 0,0,0);
        acc2[nt] = __builtin_amdgcn_mfma_f32_16x16x32_bf16(ah, bl, acc2[nt], 0,0,0);
        acc2[nt] = __builtin_amdgcn_mfma_f32_16x16x32_bf16(al, bh, acc2[nt], 0,0,0);
      }
    }
  }
  // epilogue: rmsnorm backward; rows split over wm, cols split over wn
  float* red = (float*)wbh;   // [0..127] sgg, [128..255] ssh[2][64], [256..383] doth[2][64]
  __syncthreads();
  if (tid<128) red[tid]=0.0f;
  float ss[4] = {0,0,0,0};
  #pragma unroll
  for (int nt=0; nt<4; nt++)
    #pragma unroll
    for (int r=0;r<4;r++) ss[r] += acc2[nt][r]*acc2[nt][r];
  #pragma unroll
  for (int m=1;m<16;m<<=1)
    #pragma unroll
    for (int r=0;r<4;r++) ss[r] += __shfl_xor(ss[r], m, 64);
  if (n_l==0){
    #pragma unroll
    for (int r=0;r<4;r++) red[128 + wn*64 + 16*wm + quad*4 + r] = ss[r];
  }
  __syncthreads();
  float rr[4];
  #pragma unroll
  for (int r=0;r<4;r++){
    int row = 16*wm + quad*4 + r;
    float tot = red[128 + row] + red[128 + 64 + row];
    rr[r] = rsqrtf(tot*(1.0f/128.0f) + 1e-6f);
  }
  float gv[4];
  #pragma unroll
  for (int nt=0; nt<4; nt++) gv[nt] = mgamma[h*128 + wn*64 + nt*16 + n_l];
  float lrv[4];
  #pragma unroll
  for (int r=0;r<4;r++) lrv[r] = LRb[(tok0 + 16*wm + quad*4 + r)*4 + h]*(2.0f/128.0f);
  float dnv[4][4]; float dot[4]={0,0,0,0}; float ggp[4];
  #pragma unroll
  for (int nt=0; nt<4; nt++) ggp[nt]=0.0f;
  #pragma unroll
  for (int nt=0; nt<4; nt++)
    #pragma unroll
    for (int r=0;r<4;r++){
      int t = 16*wm + quad*4 + r;
      int d = wn*64 + nt*16 + n_l;
      float xv = Kb[(tok0+t)*512 + h*128 + d];
      float vv = Vb[(tok0+t)*512 + h*128 + d];
      float nval = acc2[nt][r]*rr[r];
      float pred = nval*gv[nt] + xv;
      float dp = lrv[r]*(pred - vv);
      ggp[nt] += dp*nval;
      float dn = dp*gv[nt];
      dnv[nt][r] = dn;
      dot[r] += dn*acc2[nt][r];
    }
  #pragma unroll
  for (int nt=0; nt<4; nt++) atomicAdd(&red[wn*64 + nt*16 + n_l], ggp[nt]);
  #pragma unroll
  for (int m=1;m<16;m<<=1)
    #pragma unroll
    for (int r=0;r<4;r++) dot[r] += __shfl_xor(dot[r], m, 64);
  if (n_l==0){
    #pragma unroll
    for (int r=0;r<4;r++) red[256 + wn*64 + 16*wm + quad*4 + r] = dot[r];
  }
  __syncthreads();
  #pragma unroll
  for (int r=0;r<4;r++){
    int row = 16*wm + quad*4 + r;
    float dtot = red[256 + row] + red[256 + 64 + row];
    float dt = dtot*rr[r]*rr[r]*rr[r]*(1.0f/128.0f);
    #pragma unroll
    for (int nt=0; nt<4; nt++){
      int d = wn*64 + nt*16 + n_l;
      DH2[(size_t)inst*8192 + (size_t)row*128 + d] = rr[r]*dnv[nt][r] - dt*acc2[nt][r];
    }
  }
  __syncthreads();
  if (tid<128) GG[(size_t)inst*128+tid] = -red[tid];
}

// ---------------- dw2 (MFMA, 512 thr): G2T[d][j] = -sum_t dh2[t,d]*gelu(h1[t,j]); norm2[256+inst] ----------------
__global__ __launch_bounds__(512) void k_dw2(const float* __restrict__ DH2, const float* __restrict__ H1T,
                                             float* __restrict__ G2T, float* __restrict__ norm2){
  int inst = blockIdx.x;
  int tid = threadIdx.x, w = tid>>6, lane = tid&63, n_l = lane&15, quad = lane>>4;
  __shared__ unsigned short d2h[8192], d2l[8192];  // dh2^T [128 d][64 t] swz64 hi/lo
  __shared__ unsigned short ath[8192], atl[8192];  // gelu(h1)^T tile [128 j][64 t] swz64 hi/lo
  float nrm = 0.0f;
  for (int it=0; it<4; it++){
    int idx = it*2048 + tid*4;
    int t = idx>>7, d = idx&127;
    float4 v = *(const float4*)(DH2 + (size_t)inst*8192 + idx);
    unsigned short hh,ll;
    hilo(v.x,hh,ll); d2h[swz64(d+0,t)]=hh; d2l[swz64(d+0,t)]=ll;
    hilo(v.y,hh,ll); d2h[swz64(d+1,t)]=hh; d2l[swz64(d+1,t)]=ll;
    hilo(v.z,hh,ll); d2h[swz64(d+2,t)]=hh; d2l[swz64(d+2,t)]=ll;
    hilo(v.w,hh,ll); d2h[swz64(d+3,t)]=hh; d2l[swz64(d+3,t)]=ll;
  }
  for (int jt=0; jt<4; jt++){
    int j0 = jt*128;
    if (jt) __syncthreads();
    for (int it=0; it<4; it++){
      int idx = it*2048 + tid*4;
      int j = idx>>6, t = idx&63;
      float4 v = *(const float4*)(H1T + (size_t)inst*32768 + (size_t)(j0+j)*64 + t);
      union { unsigned long long q; unsigned short s[4]; } uh, ul;
      float g0=geluf(v.x), g1=geluf(v.y), g2=geluf(v.z), g3=geluf(v.w);
      hilo(g0,uh.s[0],ul.s[0]); hilo(g1,uh.s[1],ul.s[1]);
      hilo(g2,uh.s[2],ul.s[2]); hilo(g3,uh.s[3],ul.s[3]);
      int p = swz64(j,t);
      *(unsigned long long*)&ath[p] = uh.q;
      *(unsigned long long*)&atl[p] = ul.q;
    }
    __syncthreads();
    v4f acc[8];
    #pragma unroll
    for (int j=0;j<8;j++){ v4f z={0.f,0.f,0.f,0.f}; acc[j]=z; }
    #pragma unroll
    for (int ks=0; ks<2; ks++){
      int kf = ks*32 + quad*8;
      v8s ah = *(const v8s*)&d2h[swz64(16*w + n_l, kf)];
      v8s al = *(const v8s*)&d2l[swz64(16*w + n_l, kf)];
      #pragma unroll
      for (int nt=0; nt<8; nt++){
        v8s bh = *(const v8s*)&ath[swz64(nt*16+n_l, kf)];
        v8s bl = *(const v8s*)&atl[swz64(nt*16+n_l, kf)];
        acc[nt] = __builtin_amdgcn_mfma_f32_16x16x32_bf16(ah, bh, acc[nt], 0,0,0);
        acc[nt] = __builtin_amdgcn_mfma_f32_16x16x32_bf16(ah, bl, acc[nt], 0,0,0);
        acc[nt] = __builtin_amdgcn_mfma_f32_16x16x32_bf16(al, bh, acc[nt], 0,0,0);
      }
    }
    #pragma unroll
    for (int nt=0; nt<8; nt++)
      #pragma unroll
      for (int r=0;r<4;r++){
        float gvv = acc[nt][r];
        nrm += gvv*gvv;
        G2T[(size_t)inst*65536 + (size_t)(16*w + quad*4 + r)*512 + j0 + nt*16 + n_l] = -gvv;
      }
  }
  #pragma unroll
  for (int o=32;o>0;o>>=1) nrm += __shfl_down(nrm, o, 64);
  __syncthreads();
  float* red8 = (float*)d2h;
  if (lane==0) red8[w]=nrm;
  __syncthreads();
  if (tid==0){
    float s=0;
    #pragma unroll
    for (int i=0;i<8;i++) s+=red8[i];
    norm2[256+inst] = s;
  }
}

// ---------------- dw1 (MFMA, 512 thr, fused): da^T = w2@dh2^T; dh1 = da*gelu'; G1 = -x^T@dh1 ----------------
__global__ __launch_bounds__(512) void k_dw1(const float* __restrict__ Kb, const float* __restrict__ DH2,
    const float* __restrict__ H1T, const float* __restrict__ mw2, float* __restrict__ G1,
    float* __restrict__ norm2){
  int inst = blockIdx.x;
  int ci = inst&31, h=(inst>>5)&3, b=inst>>7;
  size_t tok0 = (size_t)b*NN_ + (size_t)ci*64;
  int tid = threadIdx.x, w = tid>>6, lane = tid&63, n_l = lane&15, quad = lane>>4;
  int wm = w&3, wn = w>>2;
  __shared__ unsigned short dh2h[8192];   // dh2 [64 t][128 d] swz, hi
  __shared__ unsigned short xth[8192];    // x^T [128 d][64 t] swz64, hi
  __shared__ unsigned short wb[16384];    // w2 tile hi/lo; reused for dh1T hi/lo
  unsigned short* wbl = wb + 8192;
  unsigned short* d1h = wb;
  unsigned short* d1l = wb + 4096;
  const float* w2 = mw2 + (size_t)h*65536;
  float nrm = 0.0f;
  for (int it=0; it<4; it++){
    int idx = it*2048 + tid*4;
    int t = idx>>7, d = idx&127;
    float4 v = *(const float4*)(DH2 + (size_t)inst*8192 + idx);
    union { unsigned long long q; unsigned short s[4]; } uh;
    uh.s[0]=f2bs(v.x); uh.s[1]=f2bs(v.y); uh.s[2]=f2bs(v.z); uh.s[3]=f2bs(v.w);
    *(unsigned long long*)&dh2h[swz(t,d)] = uh.q;
  }
  for (int it=0; it<4; it++){
    int idx = it*2048 + tid*4;
    int t = idx>>7, d = idx&127;
    float4 v = *(const float4*)(Kb + (tok0+t)*512 + h*128 + d);
    xth[swz64(d+0,t)] = f2bs(v.x);
    xth[swz64(d+1,t)] = f2bs(v.y);
    xth[swz64(d+2,t)] = f2bs(v.z);
    xth[swz64(d+3,t)] = f2bs(v.w);
  }
  for (int jt=0; jt<8; jt++){
    int j0 = jt*64;
    __syncthreads();
    for (int it=0; it<4; it++){
      int idx = it*2048 + tid*4;
      int jj = idx>>7, d = idx&127;
      float4 v = *(const float4*)(w2 + (size_t)(j0+jj)*128 + d);
      union { unsigned long long q; unsigned short s[4]; } uh, ul;
      hilo(v.x,uh.s[0],ul.s[0]); hilo(v.y,uh.s[1],ul.s[1]);
      hilo(v.z,uh.s[2],ul.s[2]); hilo(v.w,uh.s[3],ul.s[3]);
      int p = swz(jj,d);
      *(unsigned long long*)&wb[p]  = uh.q;
      *(unsigned long long*)&wbl[p] = ul.q;
    }
    __syncthreads();
    // daT: wave (wm,wn): M j-row 16*wm; N t-tiles wn*32+{0,16}; K=128 d
    v4f da[2];
    #pragma unroll
    for (int nt=0; nt<2; nt++){ v4f z={0.f,0.f,0.f,0.f}; da[nt]=z; }
    #pragma unroll
    for (int ks=0; ks<4; ks++){
      int kf = ks*32 + quad*8;
      v8s a_h = *(const v8s*)&wb[swz(16*wm + n_l, kf)];
      v8s a_l = *(const v8s*)&wbl[swz(16*wm + n_l, kf)];
      #pragma unroll
      for (int nt=0; nt<2; nt++){
        v8s bv = *(const v8s*)&dh2h[swz(wn*32 + nt*16 + n_l, kf)];
        da[nt] = __builtin_amdgcn_mfma_f32_16x16x32_bf16(a_h, bv, da[nt], 0,0,0);
        da[nt] = __builtin_amdgcn_mfma_f32_16x16x32_bf16(a_l, bv, da[nt], 0,0,0);
      }
    }
    __syncthreads();
    // dh1T = daT * gelu'(h1T): wave covers (16 j) x (32 t)
    #pragma unroll
    for (int nt=0; nt<2; nt++)
      #pragma unroll
      for (int r=0;r<4;r++){
        int jl = 16*wm + quad*4 + r;
        int t = wn*32 + nt*16 + n_l;
        float hv = H1T[(size_t)inst*32768 + (size_t)(j0+jl)*64 + t];
        float d1 = da[nt][r]*gelupf(hv);
        unsigned short hs = f2bs(d1);
        d1h[swz64(jl,t)] = hs;
        d1l[swz64(jl,t)] = f2bs(d1 - bs2f(hs));
      }
    __syncthreads();
    // G1 tile: wave w: M d-row 16w; N=64 j (4 nt); K=64 t
    v4f g[4];
    #pragma unroll
    for (int nt=0; nt<4; nt++){ v4f z={0.f,0.f,0.f,0.f}; g[nt]=z; }
    #pragma unroll
    for (int ks=0; ks<2; ks++){
      int kf = ks*32 + quad*8;
      v8s a_ = *(const v8s*)&xth[swz64(16*w + n_l, kf)];
      #pragma unroll
      for (int nt=0; nt<4; nt++){
        v8s bh = *(const v8s*)&d1h[swz64(nt*16+n_l, kf)];
        v8s bl = *(const v8s*)&d1l[swz64(nt*16+n_l, kf)];
        g[nt] = __builtin_amdgcn_mfma_f32_16x16x32_bf16(a_, bh, g[nt], 0,0,0);
        g[nt] = __builtin_amdgcn_mfma_f32_16x16x32_bf16(a_, bl, g[nt], 0,0,0);
      }
    }
    #pragma unroll
    for (int nt=0; nt<4; nt++)
      #pragma unroll
      for (int r=0;r<4;r++){
        float gvv = g[nt][r];
        nrm += gvv*gvv;
        G1[(size_t)inst*65536 + (size_t)(16*w + quad*4 + r)*512 + j0 + nt*16 + n_l] = -gvv;
      }
  }
  #pragma unroll
  for (int o=32;o>0;o>>=1) nrm += __shfl_down(nrm, o, 64);
  __syncthreads();
  float* red8 = (float*)wb;
  if (lane==0) red8[w]=nrm;
  __syncthreads();
  if (tid==0){
    float s=0;
    #pragma unroll
    for (int i=0;i<8;i++) s+=red8[i];
    norm2[inst] = s;
  }
}

// ---------------- NS fused A+B (512 thr): A = t@t^T (regs); B' = CC*A@A + CB*A + CA*I ----------------
__global__ __launch_bounds__(512) void k_nsAB(const float* __restrict__ G1, const float* __restrict__ G2T,
                                              const float* __restrict__ norm2,
                                              unsigned short* __restrict__ ABh, unsigned short* __restrict__ ABl,
                                              int first){
  int m = blockIdx.x;
  const float* t = (m<256)? (G1 + (size_t)m*65536) : (G2T + (size_t)(m-256)*65536);
  float scl = first ? 1.0f/fmaxf(sqrtf(norm2[m]), 1e-7f) : 1.0f;
  __shared__ unsigned short th[16384];
  __shared__ unsigned short tl[16384];
  int tid = threadIdx.x;
  int w = tid>>6, lane = tid&63;     // w: 0..7, rows 16w
  int n = lane&15, quad = lane>>4;
  v4f acc[8];
  #pragma unroll
  for (int j=0;j<8;j++){ v4f z = {0.f,0.f,0.f,0.f}; acc[j]=z; }
  for (int c=0;c<4;c++){
    int k0 = c*128;
    for (int it=0; it<8; it++){
      int idx = it*2048 + tid*4;
      int r = idx>>7, k = idx&127;
      float4 v = *(const float4*)(t + (size_t)r*512 + k0 + k);
      v.x*=scl; v.y*=scl; v.z*=scl; v.w*=scl;
      union { unsigned long long q; unsigned short s[4]; } uh, ulw;
      hilo(v.x,uh.s[0],ulw.s[0]); hilo(v.y,uh.s[1],ulw.s[1]);
      hilo(v.z,uh.s[2],ulw.s[2]); hilo(v.w,uh.s[3],ulw.s[3]);
      *(unsigned long long*)&th[swz(r,k)] = uh.q;
      *(unsigned long long*)&tl[swz(r,k)] = ulw.q;
    }
    __syncthreads();
    for (int kk=0; kk<128; kk+=32){
      int kf = kk + quad*8;
      v8s ah = *(const v8s*)&th[swz(16*w + n, kf)];
      v8s al = *(const v8s*)&tl[swz(16*w + n, kf)];
      #pragma unroll
      for (int j=0;j<8;j++){
        v8s bh = *(const v8s*)&th[swz(j*16 + n, kf)];
        v8s bl = *(const v8s*)&tl[swz(j*16 + n, kf)];
        acc[j] = __builtin_amdgcn_mfma_f32_16x16x32_bf16(ah, bh, acc[j], 0,0,0);
        acc[j] = __builtin_amdgcn_mfma_f32_16x16x32_bf16(ah, bl, acc[j], 0,0,0);
        acc[j] = __builtin_amdgcn_mfma_f32_16x16x32_bf16(al, bh, acc[j], 0,0,0);
      }
    }
    __syncthreads();
  }
  const float CA=3.4445f, CB=-4.775f, CC=2.0315f, CBoverCC = CB/CC;
  #pragma unroll
  for (int j=0;j<8;j++)
    #pragma unroll
    for (int r=0;r<4;r++){
      int row = 16*w + quad*4 + r;
      int col = j*16 + n;
      float av = acc[j][r];
      unsigned short hs, ls;
      hilo(av, hs, ls);
      th[swz(row,col)] = hs;
      tl[swz(row,col)] = ls;
      acc[j][r] = CBoverCC*av;
    }
  __syncthreads();
  for (int kk=0; kk<128; kk+=32){
    int kf = kk + quad*8;
    v8s ah = *(const v8s*)&th[swz(16*w + n, kf)];
    v8s al = *(const v8s*)&tl[swz(16*w + n, kf)];
    #pragma unroll
    for (int j=0;j<8;j++){
      v8s bh = *(const v8s*)&th[swz(j*16 + n, kf)];
      v8s bl = *(const v8s*)&tl[swz(j*16 + n, kf)];
      acc[j] = __builtin_amdgcn_mfma_f32_16x16x32_bf16(ah, bh, acc[j], 0,0,0);
      acc[j] = __builtin_amdgcn_mfma_f32_16x16x32_bf16(ah, bl, acc[j], 0,0,0);
      acc[j] = __builtin_amdgcn_mfma_f32_16x16x32_bf16(al, bh, acc[j], 0,0,0);
    }
  }
  __syncthreads();
  #pragma unroll
  for (int j=0;j<8;j++)
    #pragma unroll
    for (int r=0;r<4;r++){
      int row = 16*w + quad*4 + r;
      int col = j*16 + n;
      float v = CC*acc[j][r];
      if (row == col) v += CA;        // fold a*t passthrough: B' = B + CA*I
      unsigned short hs, ls;
      hilo(v, hs, ls);
      th[row*128+col] = hs;
      tl[row*128+col] = ls;
    }
  __syncthreads();
  for (int it=0; it<4; it++){
    int idx = it*4096 + tid*8;
    *(v8s*)&ABh[(size_t)m*16384 + idx] = *(const v8s*)&th[idx];
    *(v8s*)&ABl[(size_t)m*16384 + idx] = *(const v8s*)&tl[idx];
  }
}

// ---------------- NS step 2 (512 thr): t' = B'@t per 128-col strip (pure matmul), XCD swizzle ----------------
__global__ __launch_bounds__(512) void k_nsZ(float* __restrict__ G1, float* __restrict__ G2T,
                                             const unsigned short* __restrict__ ABh, const unsigned short* __restrict__ ABl,
                                             const float* __restrict__ norm2, int first){
  int blk = blockIdx.x;
  int m = (blk>>5)*8 + (blk&7);
  int s = (blk>>3)&3, c0 = s*128;
  float* t = (m<256)? (G1 + (size_t)m*65536) : (G2T + (size_t)(m-256)*65536);
  float scl = first ? 1.0f/fmaxf(sqrtf(norm2[m]), 1e-7f) : 1.0f;
  __shared__ __align__(16) unsigned char smem[65536];
  unsigned short* Bh = (unsigned short*)smem;
  unsigned short* Bl = Bh + 8192;
  unsigned short* uh = Bh + 16384;
  unsigned short* ul = Bh + 24576;
  float* Zs = (float*)smem;
  int tid = threadIdx.x;
  int w = tid>>6, lane = tid&63;      // w: 0..7, rows 16w
  int n = lane&15, quad = lane>>4;
  v4f acc[8];
  #pragma unroll
  for (int j=0;j<8;j++){ v4f z = {0.f,0.f,0.f,0.f}; acc[j]=z; }
  for (int c=0;c<2;c++){
    int k0 = c*64;
    for (int it=0; it<2; it++){
      int idx = it*4096 + tid*8;
      int r = idx>>6, k = idx&63;
      *(v8s*)&Bh[swz64(r,k)] = *(const v8s*)&ABh[(size_t)m*16384 + (size_t)r*128 + k0 + k];
      *(v8s*)&Bl[swz64(r,k)] = *(const v8s*)&ABl[(size_t)m*16384 + (size_t)r*128 + k0 + k];
    }
    for (int it=0; it<4; it++){
      int idx = it*2048 + tid*4;
      int kr = idx>>7, j = idx&127;
      float4 v = *(const float4*)(t + (size_t)(k0+kr)*512 + c0 + j);
      float vv[4] = {v.x*scl, v.y*scl, v.z*scl, v.w*scl};
      #pragma unroll
      for (int e=0;e<4;e++){
        unsigned short hs = f2bs(vv[e]);
        uh[swz64(j+e, kr)] = hs;
        ul[swz64(j+e, kr)] = f2bs(vv[e] - bs2f(hs));
      }
    }
    __syncthreads();
    #pragma unroll
    for (int kk=0; kk<64; kk+=32){
      int kf = kk + quad*8;
      v8s ah = *(const v8s*)&Bh[swz64(16*w + n, kf)];
      v8s al = *(const v8s*)&Bl[swz64(16*w + n, kf)];
      #pragma unroll
      for (int j=0;j<8;j++){
        v8s bh = *(const v8s*)&uh[swz64(j*16 + n, kf)];
        v8s bl = *(const v8s*)&ul[swz64(j*16 + n, kf)];
        acc[j] = __builtin_amdgcn_mfma_f32_16x16x32_bf16(ah, bh, acc[j], 0,0,0);
        acc[j] = __builtin_amdgcn_mfma_f32_16x16x32_bf16(ah, bl, acc[j], 0,0,0);
        acc[j] = __builtin_amdgcn_mfma_f32_16x16x32_bf16(al, bh, acc[j], 0,0,0);
      }
    }
    __syncthreads();
  }
  #pragma unroll
  for (int j=0;j<8;j++)
    #pragma unroll
    for (int r=0;r<4;r++)
      Zs[(16*w + quad*4 + r)*128 + j*16 + n] = acc[j][r];
  __syncthreads();
  for (int it=0; it<8; it++){
    int idx = it*2048 + tid*4;
    int i = idx>>7, j = idx&127;
    *(float4*)(t + (size_t)i*512 + c0 + j) = *(const float4*)&Zs[i*128+j];
  }
}

// ---------------- momentum + decay scans (float4/thread, prefetch), per (b,h) strand ----------------
__global__ __launch_bounds__(256) void k_scan_mat(float* __restrict__ G, const float* __restrict__ mw,
    const float* __restrict__ MOMb, const float* __restrict__ DECb, int transposed){
  int bh = blockIdx.x>>6;
  int eblk = blockIdx.x&63;
  int e = (eblk*256 + threadIdx.x)*4;
  int h = bh&3;
  float4 u;
  if (transposed){
    int d = e>>9; int j = e&511;
    u.x = mw[(size_t)h*65536 + (size_t)(j+0)*128 + d];
    u.y = mw[(size_t)h*65536 + (size_t)(j+1)*128 + d];
    u.z = mw[(size_t)h*65536 + (size_t)(j+2)*128 + d];
    u.w = mw[(size_t)h*65536 + (size_t)(j+3)*128 + d];
  } else {
    u = *(const float4*)(mw + (size_t)h*65536 + e);
  }
  float4 mval = {0,0,0,0};
  size_t base = (size_t)(bh*32)*65536 + e;
  float4 s = *(const float4*)(G + base);
  for (int ci=0; ci<32; ci++){
    size_t off = base + (size_t)ci*65536;
    float4 s_next;
    if (ci<31) s_next = *(const float4*)(G + off + 65536);
    float mo = MOMb[bh*32+ci], de = DECb[bh*32+ci];
    float om = 1.0f-de;
    mval.x = mo*mval.x + s.x; mval.y = mo*mval.y + s.y;
    mval.z = mo*mval.z + s.z; mval.w = mo*mval.w + s.w;
    u.x = om*u.x + mval.x; u.y = om*u.y + mval.y;
    u.z = om*u.z + mval.z; u.w = om*u.w + mval.w;
    *(float4*)(G + off) = u;
    s = s_next;
  }
}

__global__ __launch_bounds__(128) void k_scan_gamma(float* __restrict__ GG, const float* __restrict__ mg,
    const float* __restrict__ MOMb, const float* __restrict__ DECb){
  int bh=blockIdx.x; int e=threadIdx.x; int h=bh&3;
  float u = mg[h*128+e]; float mval=0;
  for (int ci=0;ci<32;ci++){
    size_t off = ((size_t)(bh*32+ci))*128 + e;
    float s = GG[off];
    float mo = MOMb[bh*32+ci], de = DECb[bh*32+ci];
    mval = mo*mval + s;
    u = (1.0f-de)*u + mval;
    GG[off]=u;
  }
}

// ---------------- retrieval (MFMA, 512 thr, 4x2 wave grid) ----------------
__global__ __launch_bounds__(512) void k_retr(const float* __restrict__ Qb, const float* __restrict__ G1,
   const float* __restrict__ G2T, const float* __restrict__ GG, const float* __restrict__ mw1,
   const float* __restrict__ mw2, const float* __restrict__ mgamma,
   const float* __restrict__ GATEb, float* __restrict__ OUTT){
  int inst = blockIdx.x;
  int ci = inst & 31, h = (inst>>5)&3, b = inst>>7;
  size_t tok0 = (size_t)b*NN_ + (size_t)ci*64;
  int tid = threadIdx.x, w = tid>>6, lane = tid&63, n_l = lane&15, quad = lane>>4;
  int wm = w&3, wn = w>>2;
  __shared__ unsigned short xh[8192];
  __shared__ unsigned short wbh[8192], wbl[8192];
  __shared__ unsigned short ash[4096], asl[4096];
  const int first = (ci==0);
  const float* w1 = first ? (mw1 + (size_t)h*65536) : (G1 + (size_t)(inst-1)*65536);
  const float* w2j = mw2 + (size_t)h*65536;
  const float* w2d = G2T + (size_t)(inst-1)*65536;
  for (int it=0; it<4; it++){
    int idx = it*2048 + tid*4;
    int r = idx>>7, d = idx&127;
    float4 v = *(const float4*)(Qb + (tok0+r)*512 + h*128 + d);
    int p = swz(r,d);
    *(unsigned*)&xh[p]   = (unsigned)f2bs(v.x)|((unsigned)f2bs(v.y)<<16);
    *(unsigned*)&xh[p+2] = (unsigned)f2bs(v.z)|((unsigned)f2bs(v.w)<<16);
  }
  v4f acc2[4];
  #pragma unroll
  for (int j=0;j<4;j++){ v4f z={0.f,0.f,0.f,0.f}; acc2[j]=z; }
  for (int jt=0; jt<8; jt++){
    int j0 = jt*64;
    __syncthreads();
    for (int it=0; it<4; it++){
      int idx = it*2048 + tid*4;
      int d = idx>>6, jj = idx&63;
      float4 v = *(const float4*)(w1 + (size_t)d*512 + j0 + jj);
      unsigned short hh,ll;
      hilo(v.x,hh,ll); wbh[swz(jj+0,d)]=hh; wbl[swz(jj+0,d)]=ll;
      hilo(v.y,hh,ll); wbh[swz(jj+1,d)]=hh; wbl[swz(jj+1,d)]=ll;
      hilo(v.z,hh,ll); wbh[swz(jj+2,d)]=hh; wbl[swz(jj+2,d)]=ll;
      hilo(v.w,hh,ll); wbh[swz(jj+3,d)]=hh; wbl[swz(jj+3,d)]=ll;
    }
    __syncthreads();
    v4f acc1[2];
    #pragma unroll
    for (int nt=0; nt<2; nt++){ v4f z={0.f,0.f,0.f,0.f}; acc1[nt]=z; }
    #pragma unroll
    for (int ks=0; ks<4; ks++){
      int kf = ks*32 + quad*8;
      v8s av = *(const v8s*)&xh[swz(16*wm + n_l, kf)];
      #pragma unroll
      for (int nt=0; nt<2; nt++){
        int jj = wn*32 + nt*16 + n_l;
        v8s bh = *(const v8s*)&wbh[swz(jj, kf)];
        v8s bl = *(const v8s*)&wbl[swz(jj, kf)];
        acc1[nt] = __builtin_amdgcn_mfma_f32_16x16x32_bf16(av, bh, acc1[nt], 0,0,0);
        acc1[nt] = __builtin_amdgcn_mfma_f32_16x16x32_bf16(av, bl, acc1[nt], 0,0,0);
      }
    }
    #pragma unroll
    for (int nt=0; nt<2; nt++)
      #pragma unroll
      for (int r=0;r<4;r++){
        int t = 16*wm + quad*4 + r;
        int jj = wn*32 + nt*16 + n_l;
        float g = geluf(acc1[nt][r]);
        unsigned short gh = f2bs(g);
        ash[swz64(t, jj)] = gh;
        asl[swz64(t, jj)] = f2bs(g - bs2f(gh));
      }
    __syncthreads();
    if (first){
      for (int it=0; it<4; it++){
        int idx = it*2048 + tid*4;
        int jj = idx>>7, d = idx&127;
        float4 v = *(const float4*)(w2j + (size_t)(j0+jj)*128 + d);
        unsigned short hh,ll;
        hilo(v.x,hh,ll); wbh[swz64(d+0,jj)]=hh; wbl[swz64(d+0,jj)]=ll;
        hilo(v.y,hh,ll); wbh[swz64(d+1,jj)]=hh; wbl[swz64(d+1,jj)]=ll;
        hilo(v.z,hh,ll); wbh[swz64(d+2,jj)]=hh; wbl[swz64(d+2,jj)]=ll;
        hilo(v.w,hh,ll); wbh[swz64(d+3,jj)]=hh; wbl[swz64(d+3,jj)]=ll;
      }
    } else {
      for (int it=0; it<4; it++){
        int idx = it*2048 + tid*4;
        int d = idx>>6, jj = idx&63;
        float4 v = *(const float4*)(w2d + (size_t)d*512 + j0 + jj);
        unsigned short h0,h1,h2,h3,l0,l1,l2,l3;
        hilo(v.x,h0,l0); hilo(v.y,h1,l1); hilo(v.z,h2,l2); hilo(v.w,h3,l3);
        int p = swz64(d,jj);
        *(unsigned*)&wbh[p]   = (unsigned)h0|((unsigned)h1<<16);
        *(unsigned*)&wbh[p+2] = (unsigned)h2|((unsigned)h3<<16);
        *(unsigned*)&wbl[p]   = (unsigned)l0|((unsigned)l1<<16);
        *(unsigned*)&wbl[p+2] = (unsigned)l2|((unsigned)l3<<16);
      }
    }
    __syncthreads();
    #pragma unroll
    for (int ks=0; ks<2; ks++){
      int kf = ks*32 + quad*8;
      v8s ah = *(const v8s*)&ash[swz64(16*wm + n_l, kf)];
      v8s al = *(const v8s*)&asl[swz64(16*wm + n_l, kf)];
      #pragma unroll
      for (int nt=0; nt<4; nt++){
        int dc = wn*64 + nt*16 + n_l;
        v8s bh = *(const v8s*)&wbh[swz64(dc, kf)];
        v8s bl = *(const v8s*)&wbl[swz64(dc, kf)];
        acc2[nt] = __builtin_amdgcn_mfma_f32_16x16x32_bf16(ah, bh, acc2[nt], 0,0,0);
        acc2[nt] = __builtin_amdgcn_mfma_f32_16x16x32_bf16(ah, bl, acc2[nt], 0,0,0);
        acc2[nt] = __builtin_amdgcn_mfma_f32_16x16x32_bf16(al, bh, acc2[nt], 0,0,0);
      }
    }
  }
  float* red = (float*)wbh;   // [0..127]: ssh[2][64]
  __syncthreads();
  float ss[4] = {0,0,0,0};
  #pragma unroll
  for (int nt=0; nt<4; nt++)
    #pragma unroll
    for (int r=0;r<4;r++) ss[r] += acc2[nt][r]*acc2[nt][r];
  #pragma unroll
  for (int m=1;m<16;m<<=1)
    #pragma unroll
    for (int r=0;r<4;r++) ss[r] += __shfl_xor(ss[r], m, 64);
  if (n_l==0){
    #pragma unroll
    for (int r=0;r<4;r++) red[wn*64 + 16*wm + quad*4 + r] = ss[r];
  }
  __syncthreads();
  float rr[4];
  #pragma unroll
  for (int r=0;r<4;r++){
    int row = 16*wm + quad*4 + r;
    float tot = red[row] + red[64 + row];
    rr[r] = rsqrtf(tot*(1.0f/128.0f) + 1e-6f);
  }
  float gv[4];
  #pragma unroll
  for (int nt=0; nt<4; nt++){
    int d = wn*64 + nt*16 + n_l;
    gv[nt] = first ? mgamma[h*128+d] : GG[(size_t)(inst-1)*128+d];
  }
  float gate[4];
  #pragma unroll
  for (int r=0;r<4;r++) gate[r] = GATEb[(tok0 + 16*wm + quad*4 + r)*4 + h];
  #pragma unroll
  for (int nt=0; nt<4; nt++)
    #pragma unroll
    for (int r=0;r<4;r++){
      int t = 16*wm + quad*4 + r;
      int d = wn*64 + nt*16 + n_l;
      float qv = Qb[(tok0+t)*512 + h*128 + d];
      OUTT[(tok0+t)*512 + h*128 + d] = (acc2[nt][r]*rr[r]*gv[nt] + qv)*gate[r];
    }
}

extern "C" void kernel_launch(void* const* d_in, const int* in_sizes, int n_in,
                              void* d_out, int out_size, void* d_ws, size_t ws_size,
                              hipStream_t stream) {
  (void)in_sizes; (void)n_in; (void)out_size; (void)ws_size;
  const float* seq   = (const float*)d_in[0];
  const float* sg    = (const float*)d_in[1];
  const float* rg    = (const float*)d_in[2];
  const float* Wq    = (const float*)d_in[3];
  const float* Wk    = (const float*)d_in[4];
  const float* Wv    = (const float*)d_in[5];
  const float* Wlr   = (const float*)d_in[6];
  const float* blr   = (const float*)d_in[7];
  const float* Wm    = (const float*)d_in[8];
  const float* bm    = (const float*)d_in[9];
  const float* Wd    = (const float*)d_in[10];
  const float* bd    = (const float*)d_in[11];
  const float* Wgate = (const float*)d_in[12];
  const float* Wc    = (const float*)d_in[13];
  const float* mw1   = (const float*)d_in[14];
  const float* mw2   = (const float*)d_in[15];
  const float* mgam  = (const float*)d_in[16];

  float* W = (float*)d_ws;
  float* S    = W + 0;
  float* SR   = W + 2097152;
  float* Kb   = W + 4194304;
  float* Vb   = W + 6291456;
  float* H1T  = W + 8388608;
  float* DH2  = W + 16777216;
  float* Qb   = W + 18874368;
  float* LRb  = W + 20971520;
  float* GATEb= W + 20987904;
  float* MOMb = W + 21004288;
  float* DECb = W + 21004544;
  float* GGb  = W + 21004800;
  float* G1   = W + 21037568;
  float* G2T  = W + 37814784;
  float* NRM2 = W + 54592000;   // 512 floats
  unsigned short* ABh = (unsigned short*)(W + 0);        // overlay S+SR (dead by NS time)
  unsigned short* ABl = (unsigned short*)(W + 4194304);  // overlay Kb+Vb (dead after k_dw1)
  float* OUTT = W + 8388608;  // overlay H1T slot (free by retrieval time)

  k_rmsnorm<<<4096,256,0,stream>>>(seq, sg, rg, S, SR);
  dim3 gg(64,4);
  k_gemm_mfma<<<gg,256,0,stream>>>(S,  Wk, Kb);
  k_gemm_mfma<<<gg,256,0,stream>>>(S,  Wv, Vb);
  k_gemm_mfma<<<gg,256,0,stream>>>(SR, Wq, Qb);
  k_small<<<64,256,0,stream>>>(S, SR, Wlr, blr, Wm, bm, Wd, bd, Wgate, LRb, GATEb, MOMb, DECb);
  k_fwd<<<256,512,0,stream>>>(Kb, Vb, LRb, mw1, mw2, mgam, H1T, DH2, GGb);
  k_dw2<<<256,512,0,stream>>>(DH2, H1T, G2T, NRM2);
  k_dw1<<<256,512,0,stream>>>(Kb, DH2, H1T, mw2, G1, NRM2);
  for (int it=0; it<5; it++){
    k_nsAB<<<512,512,0,stream>>>(G1, G2T, NRM2, ABh, ABl, it==0);
    k_nsZ<<<2048,512,0,stream>>>(G1, G2T, ABh, ABl, NRM2, it==0);
  }
  k_scan_mat<<<512,256,0,stream>>>(G1,  mw1, MOMb, DECb, 0);
  k_scan_mat<<<512,256,0,stream>>>(G2T, mw2, MOMb, DECb, 1);
  k_scan_gamma<<<8,128,0,stream>>>(GGb, mgam, MOMb, DECb);
  k_retr<<<256,512,0,stream>>>(Qb, G1, G2T, GGb, mw1, mw2, mgam, GATEb, OUTT);
  k_gemm_mfma<<<gg,256,0,stream>>>(OUTT, Wc, (float*)d_out);
}